// Round 14
// baseline (154.481 us; speedup 1.0000x reference)
//
#include <hip/hip_runtime.h>

#define N_NODES 100000
#define N_EDGES 1600000
#define FT 128

#define BROWS 64    // rows per bucket
#define NBUCK 1563  // ceil(N_NODES / 64)
#define EPB 4096    // edges per partition block
#define NBLKP ((N_EDGES + EPB - 1) / EPB)  // 391 partition blocks
#define CAP 1536    // staged edges per bucket (avg 1023, +16 sigma)

// ---- workspace layout (bytes) ----------------------------------------------
// h_bf        [0,           25,600,000)   N_NODES*FT*2 (bf16)
// bucketed    [25,600,000,  38,400,000)   N_EDGES int2 (packed row6|col, val)
// blkhist     [38,400,000,  40,844,532)   NBLKP*NBUCK ints (block-major)
// btot        [40,844,532,  40,850,784)   NBUCK ints
// bucket_base [40,850,784,  40,857,044)   NBUCK+1 ints
#define OFF_H 0
#define OFF_BUCKETED 25600000
#define OFF_BLKHIST 38400000
#define OFF_BTOT 40844532
#define OFF_BBASE 40850784
#define WS_NEEDED 40857044

typedef __attribute__((ext_vector_type(8))) short bf16x8;
typedef __attribute__((ext_vector_type(4))) float f32x4;

// bf16 helpers (RNE pack, shift-unpack).
static __device__ __forceinline__ ushort f2bf(float f) {
  const unsigned u = __float_as_uint(f);
  return (ushort)((u + 0x7FFF + ((u >> 16) & 1)) >> 16);
}
static __device__ __forceinline__ float bf2f(ushort s) {
  return __uint_as_float((unsigned)s << 16);
}

// ---------------------------------------------------------------------------
// Kernel 1: dense projection  h = x @ W + b  (bf16 output) via MFMA.
// Block = 256 threads (4 waves); wave = 64 rows x 128 cols.
// ---------------------------------------------------------------------------
__global__ __launch_bounds__(256) void gemm_bias_kernel(
    const float* __restrict__ x,
    const float* __restrict__ W,
    const float* __restrict__ b,
    ushort* __restrict__ h) {
  __shared__ __align__(16) ushort whi[16384];
  __shared__ __align__(16) ushort wlo[16384];

  const int tid = threadIdx.x;

  for (int idx = tid; idx < 16384; idx += 256) {
    const int k = idx >> 7;
    const int col = idx & 127;
    const float wv = W[idx];
    const ushort hi = f2bf(wv);
    const ushort lo = f2bf(wv - bf2f(hi));
    const int lane_ = (((k >> 3) & 3) << 4) | (col & 15);
    const int pos = ((((k >> 5) << 3) + (col >> 4)) * 64 + lane_) * 8 + (k & 7);
    whi[pos] = hi;
    wlo[pos] = lo;
  }
  __syncthreads();

  const int w = tid >> 6;
  const int lane = tid & 63;
  const int r0 = blockIdx.x * 256 + w * 64;
  const int arow = lane & 15;
  const int kgrp = (lane >> 4) << 3;

  float bias_v[8];
#pragma unroll
  for (int ct = 0; ct < 8; ++ct) bias_v[ct] = b[ct * 16 + (lane & 15)];

  f32x4 acc[4][8];
#pragma unroll
  for (int rf = 0; rf < 4; ++rf)
#pragma unroll
    for (int ct = 0; ct < 8; ++ct) acc[rf][ct] = (f32x4){0.f, 0.f, 0.f, 0.f};

#pragma unroll
  for (int ks = 0; ks < 4; ++ks) {
    bf16x8 afr[4];
#pragma unroll
    for (int rf = 0; rf < 4; ++rf) {
      int r = r0 + rf * 16 + arow;
      r = (r < N_NODES) ? r : (N_NODES - 1);
      const float* xp = x + (size_t)r * FT + ks * 32 + kgrp;
      const float4 u0 = *(const float4*)xp;
      const float4 u1 = *(const float4*)(xp + 4);
      bf16x8 a;
      a[0] = (short)f2bf(u0.x);
      a[1] = (short)f2bf(u0.y);
      a[2] = (short)f2bf(u0.z);
      a[3] = (short)f2bf(u0.w);
      a[4] = (short)f2bf(u1.x);
      a[5] = (short)f2bf(u1.y);
      a[6] = (short)f2bf(u1.z);
      a[7] = (short)f2bf(u1.w);
      afr[rf] = a;
    }
#pragma unroll
    for (int ct = 0; ct < 8; ++ct) {
      const int fo = ((ks * 8 + ct) * 64 + lane) * 8;
      const bf16x8 bh = *(const bf16x8*)&whi[fo];
      const bf16x8 bl = *(const bf16x8*)&wlo[fo];
#pragma unroll
      for (int rf = 0; rf < 4; ++rf) {
        acc[rf][ct] = __builtin_amdgcn_mfma_f32_16x16x32_bf16(
            afr[rf], bh, acc[rf][ct], 0, 0, 0);
        acc[rf][ct] = __builtin_amdgcn_mfma_f32_16x16x32_bf16(
            afr[rf], bl, acc[rf][ct], 0, 0, 0);
      }
    }
  }

  const int crow0 = (lane >> 4) << 2;
  const int ccol = lane & 15;
#pragma unroll
  for (int rf = 0; rf < 4; ++rf) {
#pragma unroll
    for (int ct = 0; ct < 8; ++ct) {
      const int col = ct * 16 + ccol;
#pragma unroll
      for (int i = 0; i < 4; ++i) {
        const int row = r0 + rf * 16 + crow0 + i;
        if (row < N_NODES)
          h[(size_t)row * FT + col] = f2bf(acc[rf][ct][i] + bias_v[ct]);
      }
    }
  }
}

// ---------------------------------------------------------------------------
// Pass A: per-block LDS histogram over row buckets -> blkhist[block][bucket].
// ---------------------------------------------------------------------------
__global__ __launch_bounds__(256) void partA_kernel(
    const int* __restrict__ erows, int* __restrict__ blkhist) {
  __shared__ int cnt[NBUCK];
  const int tid = threadIdx.x;
  for (int j = tid; j < NBUCK; j += 256) cnt[j] = 0;
  __syncthreads();

  const int base4 = blockIdx.x * (EPB / 4);
#pragma unroll
  for (int it = 0; it < EPB / 4 / 256; ++it) {
    const int idx4 = base4 + it * 256 + tid;
    if (idx4 < N_EDGES / 4) {
      const int4 r = ((const int4*)erows)[idx4];
      atomicAdd(&cnt[r.x >> 6], 1);
      atomicAdd(&cnt[r.y >> 6], 1);
      atomicAdd(&cnt[r.z >> 6], 1);
      atomicAdd(&cnt[r.w >> 6], 1);
    }
  }
  __syncthreads();
  int* dst = blkhist + (size_t)blockIdx.x * NBUCK;
  for (int j = tid; j < NBUCK; j += 256) dst[j] = cnt[j];
}

// ---------------------------------------------------------------------------
// Pass B1 (coalesced): ONE THREAD PER BUCKET. Consecutive threads own
// consecutive buckets, so each loop iteration k reads/writes 256 adjacent
// ints of blkhist[k][*] -- fully coalesced. In-place exclusive prefix over
// k; total -> btot[b].
// ---------------------------------------------------------------------------
__global__ __launch_bounds__(256) void partB1_kernel(
    int* __restrict__ blkhist, int* __restrict__ btot) {
  const int b = blockIdx.x * 256 + threadIdx.x;
  if (b >= NBUCK) return;
  int run = 0;
#pragma unroll 8
  for (int k = 0; k < NBLKP; ++k) {
    int* p = blkhist + (size_t)k * NBUCK + b;
    const int v = *p;
    *p = run;
    run += v;
  }
  btot[b] = run;
}

// ---------------------------------------------------------------------------
// Pass B2: exclusive-scan btot (NBUCK entries) -> bucket_base (+ sentinel).
// 512 threads x 4 elements each.
// ---------------------------------------------------------------------------
__global__ __launch_bounds__(512) void partB2_kernel(
    const int* __restrict__ btot, int* __restrict__ bucket_base) {
  __shared__ int ps[512];
  const int t = threadIdx.x;
  const int base = t * 4;

  int c[4];
  int s = 0;
#pragma unroll
  for (int j = 0; j < 4; ++j) {
    const int idx = base + j;
    c[j] = (idx < NBUCK) ? btot[idx] : 0;
    s += c[j];
  }
  ps[t] = s;
  __syncthreads();
#pragma unroll
  for (int d = 1; d < 512; d <<= 1) {
    const int u = (t >= d) ? ps[t - d] : 0;
    __syncthreads();
    ps[t] += u;
    __syncthreads();
  }

  int run = (t == 0) ? 0 : ps[t - 1];
#pragma unroll
  for (int j = 0; j < 4; ++j) {
    const int idx = base + j;
    if (idx < NBUCK) {
      bucket_base[idx] = run;
      run += c[j];
    }
  }
  if (t == 511) bucket_base[NBUCK] = N_EDGES;
}

// ---------------------------------------------------------------------------
// Pass C: partition scatter. LDS cursors = absolute offsets; each edge goes
// to its bucket region packed as ((row&63)<<24 | col, val_bits).
// ---------------------------------------------------------------------------
__global__ __launch_bounds__(256) void partC_kernel(
    const int* __restrict__ erows,
    const int* __restrict__ ecols,
    const float* __restrict__ evals,
    const int* __restrict__ blkhist,
    const int* __restrict__ bucket_base,
    int2* __restrict__ bucketed) {
  __shared__ int cur[NBUCK];
  const int tid = threadIdx.x;
  const int* src = blkhist + (size_t)blockIdx.x * NBUCK;
  for (int j = tid; j < NBUCK; j += 256) cur[j] = src[j] + bucket_base[j];
  __syncthreads();

  const int base4 = blockIdx.x * (EPB / 4);
#pragma unroll
  for (int it = 0; it < EPB / 4 / 256; ++it) {
    const int idx4 = base4 + it * 256 + tid;
    if (idx4 < N_EDGES / 4) {
      const int4 r = ((const int4*)erows)[idx4];
      const int4 c = ((const int4*)ecols)[idx4];
      const float4 v = ((const float4*)evals)[idx4];
      int p;
      p = atomicAdd(&cur[r.x >> 6], 1);
      bucketed[p] = (int2){((r.x & 63) << 24) | c.x, __float_as_int(v.x)};
      p = atomicAdd(&cur[r.y >> 6], 1);
      bucketed[p] = (int2){((r.y & 63) << 24) | c.y, __float_as_int(v.y)};
      p = atomicAdd(&cur[r.z >> 6], 1);
      bucketed[p] = (int2){((r.z & 63) << 24) | c.z, __float_as_int(v.z)};
      p = atomicAdd(&cur[r.w >> 6], 1);
      bucketed[p] = (int2){((r.w & 63) << 24) | c.w, __float_as_int(v.w)};
    }
  }
}

// ---------------------------------------------------------------------------
// Fused sort + SpMM: one block per 64-row bucket. Stage bucket edges in LDS,
// counting-sort by row in LDS, per-row gather+FMA+ReLU, single out write.
// ~13 KB LDS, 512 threads -> 4 blocks/CU (thread-capped), 32 waves = full occ.
// ---------------------------------------------------------------------------
__global__ __launch_bounds__(512) void spmm_bucket_kernel(
    const int2* __restrict__ bucketed,
    const int* __restrict__ bucket_base,
    const ushort* __restrict__ h,
    float* __restrict__ out) {
  __shared__ int2 eds[CAP];   // 12 KB
  __shared__ int cnt[BROWS];
  __shared__ int pos[BROWS];
  __shared__ int cur[BROWS];
  const int b = blockIdx.x;
  const int t = threadIdx.x;
  const int beg = bucket_base[b];
  const int end = bucket_base[b + 1];
  const int n = end - beg;
  const int m = (n < CAP) ? n : CAP;

  if (t < BROWS) cnt[t] = 0;
  __syncthreads();

  for (int i = t; i < m; i += 512)
    atomicAdd(&cnt[((unsigned)bucketed[beg + i].x) >> 24], 1);
  __syncthreads();

  if (t < BROWS) pos[t] = cnt[t];
  __syncthreads();
#pragma unroll
  for (int d = 1; d < BROWS; d <<= 1) {
    int u = 0;
    if (t < BROWS && t >= d) u = pos[t - d];
    __syncthreads();
    if (t < BROWS) pos[t] += u;
    __syncthreads();
  }
  if (t < BROWS) {
    const int excl = pos[t] - cnt[t];
    pos[t] = excl;
    cur[t] = excl;
  }
  __syncthreads();

  for (int i = t; i < m; i += 512) {
    const int2 rec = bucketed[beg + i];
    const int r6 = ((unsigned)rec.x) >> 24;
    const int p = atomicAdd(&cur[r6], 1);
    eds[p] = (int2){rec.x & 0x00FFFFFF, rec.y};
  }
  __syncthreads();

  const int g = t >> 5;          // row group 0..15
  const int lane = t & 31;
  const int j = lane * 4;        // col base

  for (int rr = 0; rr < BROWS / 16; ++rr) {
    const int r = rr * 16 + g;   // interleaved rows for load balance
    const int row = b * BROWS + r;
    const int rbeg = pos[r];
    const int rend = cur[r];

    float a0 = 0.f, a1 = 0.f, a2 = 0.f, a3 = 0.f;
    int e = rbeg;
    for (; e + 3 < rend; e += 4) {
      const int2 p0 = eds[e];
      const int2 p1 = eds[e + 1];
      const int2 p2 = eds[e + 2];
      const int2 p3 = eds[e + 3];
      const ushort4 q0 = *(const ushort4*)(h + (size_t)p0.x * FT + j);
      const ushort4 q1 = *(const ushort4*)(h + (size_t)p1.x * FT + j);
      const ushort4 q2 = *(const ushort4*)(h + (size_t)p2.x * FT + j);
      const ushort4 q3 = *(const ushort4*)(h + (size_t)p3.x * FT + j);
      const float v0 = __int_as_float(p0.y);
      const float v1 = __int_as_float(p1.y);
      const float v2 = __int_as_float(p2.y);
      const float v3 = __int_as_float(p3.y);
      a0 = fmaf(v0, bf2f(q0.x), a0);
      a1 = fmaf(v0, bf2f(q0.y), a1);
      a2 = fmaf(v0, bf2f(q0.z), a2);
      a3 = fmaf(v0, bf2f(q0.w), a3);
      a0 = fmaf(v1, bf2f(q1.x), a0);
      a1 = fmaf(v1, bf2f(q1.y), a1);
      a2 = fmaf(v1, bf2f(q1.z), a2);
      a3 = fmaf(v1, bf2f(q1.w), a3);
      a0 = fmaf(v2, bf2f(q2.x), a0);
      a1 = fmaf(v2, bf2f(q2.y), a1);
      a2 = fmaf(v2, bf2f(q2.z), a2);
      a3 = fmaf(v2, bf2f(q2.w), a3);
      a0 = fmaf(v3, bf2f(q3.x), a0);
      a1 = fmaf(v3, bf2f(q3.y), a1);
      a2 = fmaf(v3, bf2f(q3.z), a2);
      a3 = fmaf(v3, bf2f(q3.w), a3);
    }
    for (; e < rend; ++e) {
      const int2 p0 = eds[e];
      const float v0 = __int_as_float(p0.y);
      const ushort4 q0 = *(const ushort4*)(h + (size_t)p0.x * FT + j);
      a0 = fmaf(v0, bf2f(q0.x), a0);
      a1 = fmaf(v0, bf2f(q0.y), a1);
      a2 = fmaf(v0, bf2f(q0.z), a2);
      a3 = fmaf(v0, bf2f(q0.w), a3);
    }
    if (n > CAP) {  // correctness fallback, statistically never taken
      for (int i = beg + CAP; i < end; ++i) {
        const int2 rec = bucketed[i];
        if ((int)(((unsigned)rec.x) >> 24) == r) {
          const float v0 = __int_as_float(rec.y);
          const ushort4 q0 =
              *(const ushort4*)(h + (size_t)(rec.x & 0x00FFFFFF) * FT + j);
          a0 = fmaf(v0, bf2f(q0.x), a0);
          a1 = fmaf(v0, bf2f(q0.y), a1);
          a2 = fmaf(v0, bf2f(q0.z), a2);
          a3 = fmaf(v0, bf2f(q0.w), a3);
        }
      }
    }

    if (row < N_NODES) {
      float4 o;
      o.x = fmaxf(a0, 0.f);
      o.y = fmaxf(a1, 0.f);
      o.z = fmaxf(a2, 0.f);
      o.w = fmaxf(a3, 0.f);
      *(float4*)(out + (size_t)row * FT + j) = o;
    }
  }
}

// ---------------------------------------------------------------------------
// Fallback (small ws): atomic scatter + relu on bf16 h.
// ---------------------------------------------------------------------------
__global__ __launch_bounds__(256) void edge_scatter_kernel(
    const int* __restrict__ erows,
    const int* __restrict__ ecols,
    const float* __restrict__ evals,
    const ushort* __restrict__ h,
    float* out) {
  const int tid = threadIdx.x;
  const int e = blockIdx.x * 8 + (tid >> 5);
  if (e >= N_EDGES) return;
  const int r = erows[e];
  const int c = ecols[e];
  const float v = evals[e];
  const int j = (tid & 31) * 4;
  const ushort4 q = *(const ushort4*)(h + (size_t)c * FT + j);
  float* op = out + (size_t)r * FT + j;
  atomicAdd(op + 0, v * bf2f(q.x));
  atomicAdd(op + 1, v * bf2f(q.y));
  atomicAdd(op + 2, v * bf2f(q.z));
  atomicAdd(op + 3, v * bf2f(q.w));
}

__global__ __launch_bounds__(256) void relu_kernel(float* out, int n4) {
  const int i = blockIdx.x * blockDim.x + threadIdx.x;
  if (i < n4) {
    float4 v = ((float4*)out)[i];
    v.x = fmaxf(v.x, 0.f);
    v.y = fmaxf(v.y, 0.f);
    v.z = fmaxf(v.z, 0.f);
    v.w = fmaxf(v.w, 0.f);
    ((float4*)out)[i] = v;
  }
}

extern "C" void kernel_launch(void* const* d_in, const int* in_sizes, int n_in,
                              void* d_out, int out_size, void* d_ws, size_t ws_size,
                              hipStream_t stream) {
  const float* x = (const float*)d_in[0];
  const int* erows = (const int*)d_in[1];
  const int* ecols = (const int*)d_in[2];
  const float* evals = (const float*)d_in[3];
  const float* W = (const float*)d_in[4];
  const float* b = (const float*)d_in[5];
  float* out = (float*)d_out;

  char* ws = (char*)d_ws;
  ushort* h = (ushort*)(ws + OFF_H);

  gemm_bias_kernel<<<(N_NODES + 255) / 256, 256, 0, stream>>>(x, W, b, h);

  if (ws_size >= (size_t)WS_NEEDED) {
    int2* bucketed = (int2*)(ws + OFF_BUCKETED);
    int* blkhist = (int*)(ws + OFF_BLKHIST);
    int* btot = (int*)(ws + OFF_BTOT);
    int* bucket_base = (int*)(ws + OFF_BBASE);

    partA_kernel<<<NBLKP, 256, 0, stream>>>(erows, blkhist);
    partB1_kernel<<<(NBUCK + 255) / 256, 256, 0, stream>>>(blkhist, btot);
    partB2_kernel<<<1, 512, 0, stream>>>(btot, bucket_base);
    partC_kernel<<<NBLKP, 256, 0, stream>>>(erows, ecols, evals, blkhist,
                                            bucket_base, bucketed);
    spmm_bucket_kernel<<<NBUCK, 512, 0, stream>>>(bucketed, bucket_base, h,
                                                  out);
  } else {
    hipMemsetAsync(d_out, 0, (size_t)out_size * sizeof(float), stream);
    edge_scatter_kernel<<<(N_EDGES + 7) / 8, 256, 0, stream>>>(erows, ecols,
                                                               evals, h, out);
    const int n4 = out_size / 4;
    relu_kernel<<<(n4 + 255) / 256, 256, 0, stream>>>(out, n4);
  }
}

// Round 15
// 136.984 us; speedup vs baseline: 1.1277x; 1.1277x over previous
//
#include <hip/hip_runtime.h>

#define N_NODES 100000
#define N_EDGES 1600000
#define FT 128

#define BROWS 64    // rows per bucket
#define NBUCK 1563  // ceil(N_NODES / 64)
#define EPB 4096    // edges per partition block
#define NBLKP ((N_EDGES + EPB - 1) / EPB)  // 391 partition blocks
#define CAP 1536    // staged edges per bucket (avg 1023, +16 sigma)

#define B1TILE 64   // bucket columns per partB1 block
#define B1KC 49     // k-chunk per wave: ceil(391/8)

// ---- workspace layout (bytes) ----------------------------------------------
// h_bf        [0,           25,600,000)   N_NODES*FT*2 (bf16)
// bucketed    [25,600,000,  38,400,000)   N_EDGES int2 (packed row6|col, val)
// blkhist     [38,400,000,  40,844,532)   NBLKP*NBUCK ints (block-major)
// btot        [40,844,532,  40,850,784)   NBUCK ints
// bucket_base [40,850,784,  40,857,044)   NBUCK+1 ints
#define OFF_H 0
#define OFF_BUCKETED 25600000
#define OFF_BLKHIST 38400000
#define OFF_BTOT 40844532
#define OFF_BBASE 40850784
#define WS_NEEDED 40857044

typedef __attribute__((ext_vector_type(8))) short bf16x8;
typedef __attribute__((ext_vector_type(4))) float f32x4;

// bf16 helpers (RNE pack, shift-unpack).
static __device__ __forceinline__ ushort f2bf(float f) {
  const unsigned u = __float_as_uint(f);
  return (ushort)((u + 0x7FFF + ((u >> 16) & 1)) >> 16);
}
static __device__ __forceinline__ float bf2f(ushort s) {
  return __uint_as_float((unsigned)s << 16);
}

// ---------------------------------------------------------------------------
// Kernel 1: dense projection  h = x @ W + b  (bf16 output) via MFMA.
// Block = 256 threads (4 waves); wave = 64 rows x 128 cols.
// ---------------------------------------------------------------------------
__global__ __launch_bounds__(256) void gemm_bias_kernel(
    const float* __restrict__ x,
    const float* __restrict__ W,
    const float* __restrict__ b,
    ushort* __restrict__ h) {
  __shared__ __align__(16) ushort whi[16384];
  __shared__ __align__(16) ushort wlo[16384];

  const int tid = threadIdx.x;

  for (int idx = tid; idx < 16384; idx += 256) {
    const int k = idx >> 7;
    const int col = idx & 127;
    const float wv = W[idx];
    const ushort hi = f2bf(wv);
    const ushort lo = f2bf(wv - bf2f(hi));
    const int lane_ = (((k >> 3) & 3) << 4) | (col & 15);
    const int pos = ((((k >> 5) << 3) + (col >> 4)) * 64 + lane_) * 8 + (k & 7);
    whi[pos] = hi;
    wlo[pos] = lo;
  }
  __syncthreads();

  const int w = tid >> 6;
  const int lane = tid & 63;
  const int r0 = blockIdx.x * 256 + w * 64;
  const int arow = lane & 15;
  const int kgrp = (lane >> 4) << 3;

  float bias_v[8];
#pragma unroll
  for (int ct = 0; ct < 8; ++ct) bias_v[ct] = b[ct * 16 + (lane & 15)];

  f32x4 acc[4][8];
#pragma unroll
  for (int rf = 0; rf < 4; ++rf)
#pragma unroll
    for (int ct = 0; ct < 8; ++ct) acc[rf][ct] = (f32x4){0.f, 0.f, 0.f, 0.f};

#pragma unroll
  for (int ks = 0; ks < 4; ++ks) {
    bf16x8 afr[4];
#pragma unroll
    for (int rf = 0; rf < 4; ++rf) {
      int r = r0 + rf * 16 + arow;
      r = (r < N_NODES) ? r : (N_NODES - 1);
      const float* xp = x + (size_t)r * FT + ks * 32 + kgrp;
      const float4 u0 = *(const float4*)xp;
      const float4 u1 = *(const float4*)(xp + 4);
      bf16x8 a;
      a[0] = (short)f2bf(u0.x);
      a[1] = (short)f2bf(u0.y);
      a[2] = (short)f2bf(u0.z);
      a[3] = (short)f2bf(u0.w);
      a[4] = (short)f2bf(u1.x);
      a[5] = (short)f2bf(u1.y);
      a[6] = (short)f2bf(u1.z);
      a[7] = (short)f2bf(u1.w);
      afr[rf] = a;
    }
#pragma unroll
    for (int ct = 0; ct < 8; ++ct) {
      const int fo = ((ks * 8 + ct) * 64 + lane) * 8;
      const bf16x8 bh = *(const bf16x8*)&whi[fo];
      const bf16x8 bl = *(const bf16x8*)&wlo[fo];
#pragma unroll
      for (int rf = 0; rf < 4; ++rf) {
        acc[rf][ct] = __builtin_amdgcn_mfma_f32_16x16x32_bf16(
            afr[rf], bh, acc[rf][ct], 0, 0, 0);
        acc[rf][ct] = __builtin_amdgcn_mfma_f32_16x16x32_bf16(
            afr[rf], bl, acc[rf][ct], 0, 0, 0);
      }
    }
  }

  const int crow0 = (lane >> 4) << 2;
  const int ccol = lane & 15;
#pragma unroll
  for (int rf = 0; rf < 4; ++rf) {
#pragma unroll
    for (int ct = 0; ct < 8; ++ct) {
      const int col = ct * 16 + ccol;
#pragma unroll
      for (int i = 0; i < 4; ++i) {
        const int row = r0 + rf * 16 + crow0 + i;
        if (row < N_NODES)
          h[(size_t)row * FT + col] = f2bf(acc[rf][ct][i] + bias_v[ct]);
      }
    }
  }
}

// ---------------------------------------------------------------------------
// Pass A: per-block LDS histogram over row buckets -> blkhist[block][bucket].
// ---------------------------------------------------------------------------
__global__ __launch_bounds__(256) void partA_kernel(
    const int* __restrict__ erows, int* __restrict__ blkhist) {
  __shared__ int cnt[NBUCK];
  const int tid = threadIdx.x;
  for (int j = tid; j < NBUCK; j += 256) cnt[j] = 0;
  __syncthreads();

  const int base4 = blockIdx.x * (EPB / 4);
#pragma unroll
  for (int it = 0; it < EPB / 4 / 256; ++it) {
    const int idx4 = base4 + it * 256 + tid;
    if (idx4 < N_EDGES / 4) {
      const int4 r = ((const int4*)erows)[idx4];
      atomicAdd(&cnt[r.x >> 6], 1);
      atomicAdd(&cnt[r.y >> 6], 1);
      atomicAdd(&cnt[r.z >> 6], 1);
      atomicAdd(&cnt[r.w >> 6], 1);
    }
  }
  __syncthreads();
  int* dst = blkhist + (size_t)blockIdx.x * NBUCK;
  for (int j = tid; j < NBUCK; j += 256) dst[j] = cnt[j];
}

// ---------------------------------------------------------------------------
// Pass B1 (tile scan, coalesced AND parallel): block owns 64 bucket columns;
// wave w owns k-chunk [w*B1KC, (w+1)*B1KC). Pass 1: each lane accumulates its
// bucket's chunk sum in-register (row loads are 64 consecutive ints ->
// fully coalesced per wave). Pass 2: add LDS chunk bases, re-walk writing
// the exclusive prefix in place. Last wave writes btot.
// ---------------------------------------------------------------------------
__global__ __launch_bounds__(512) void partB1_kernel(
    int* __restrict__ blkhist, int* __restrict__ btot) {
  __shared__ int chunksum[8][B1TILE];
  const int w = threadIdx.x >> 6;    // wave 0..7
  const int l = threadIdx.x & 63;    // lane
  const int b = blockIdx.x * B1TILE + l;
  const bool ok = (b < NBUCK);

  const int k0 = w * B1KC;
  const int k1 = min(k0 + B1KC, NBLKP);

  int run = 0;
  if (ok) {
    for (int k = k0; k < k1; ++k) run += blkhist[(size_t)k * NBUCK + b];
  }
  chunksum[w][l] = run;
  __syncthreads();

  int base = 0;
#pragma unroll
  for (int w2 = 0; w2 < 8; ++w2)
    if (w2 < w) base += chunksum[w2][l];

  if (ok) {
    int r2 = base;
    for (int k = k0; k < k1; ++k) {
      int* p = blkhist + (size_t)k * NBUCK + b;
      const int v = *p;
      *p = r2;
      r2 += v;
    }
    if (w == 7) btot[b] = r2;  // total over all chunks
  }
}

// ---------------------------------------------------------------------------
// Pass B2: exclusive-scan btot (NBUCK entries) -> bucket_base (+ sentinel).
// 512 threads x 4 elements each.
// ---------------------------------------------------------------------------
__global__ __launch_bounds__(512) void partB2_kernel(
    const int* __restrict__ btot, int* __restrict__ bucket_base) {
  __shared__ int ps[512];
  const int t = threadIdx.x;
  const int base = t * 4;

  int c[4];
  int s = 0;
#pragma unroll
  for (int j = 0; j < 4; ++j) {
    const int idx = base + j;
    c[j] = (idx < NBUCK) ? btot[idx] : 0;
    s += c[j];
  }
  ps[t] = s;
  __syncthreads();
#pragma unroll
  for (int d = 1; d < 512; d <<= 1) {
    const int u = (t >= d) ? ps[t - d] : 0;
    __syncthreads();
    ps[t] += u;
    __syncthreads();
  }

  int run = (t == 0) ? 0 : ps[t - 1];
#pragma unroll
  for (int j = 0; j < 4; ++j) {
    const int idx = base + j;
    if (idx < NBUCK) {
      bucket_base[idx] = run;
      run += c[j];
    }
  }
  if (t == 511) bucket_base[NBUCK] = N_EDGES;
}

// ---------------------------------------------------------------------------
// Pass C: partition scatter. LDS cursors = absolute offsets; each edge goes
// to its bucket region packed as ((row&63)<<24 | col, val_bits).
// ---------------------------------------------------------------------------
__global__ __launch_bounds__(256) void partC_kernel(
    const int* __restrict__ erows,
    const int* __restrict__ ecols,
    const float* __restrict__ evals,
    const int* __restrict__ blkhist,
    const int* __restrict__ bucket_base,
    int2* __restrict__ bucketed) {
  __shared__ int cur[NBUCK];
  const int tid = threadIdx.x;
  const int* src = blkhist + (size_t)blockIdx.x * NBUCK;
  for (int j = tid; j < NBUCK; j += 256) cur[j] = src[j] + bucket_base[j];
  __syncthreads();

  const int base4 = blockIdx.x * (EPB / 4);
#pragma unroll
  for (int it = 0; it < EPB / 4 / 256; ++it) {
    const int idx4 = base4 + it * 256 + tid;
    if (idx4 < N_EDGES / 4) {
      const int4 r = ((const int4*)erows)[idx4];
      const int4 c = ((const int4*)ecols)[idx4];
      const float4 v = ((const float4*)evals)[idx4];
      int p;
      p = atomicAdd(&cur[r.x >> 6], 1);
      bucketed[p] = (int2){((r.x & 63) << 24) | c.x, __float_as_int(v.x)};
      p = atomicAdd(&cur[r.y >> 6], 1);
      bucketed[p] = (int2){((r.y & 63) << 24) | c.y, __float_as_int(v.y)};
      p = atomicAdd(&cur[r.z >> 6], 1);
      bucketed[p] = (int2){((r.z & 63) << 24) | c.z, __float_as_int(v.z)};
      p = atomicAdd(&cur[r.w >> 6], 1);
      bucketed[p] = (int2){((r.w & 63) << 24) | c.w, __float_as_int(v.w)};
    }
  }
}

// ---------------------------------------------------------------------------
// Fused sort + SpMM: one block per 64-row bucket. Stage bucket edges in LDS,
// counting-sort by row in LDS, per-row gather+FMA+ReLU, single out write.
// ---------------------------------------------------------------------------
__global__ __launch_bounds__(512) void spmm_bucket_kernel(
    const int2* __restrict__ bucketed,
    const int* __restrict__ bucket_base,
    const ushort* __restrict__ h,
    float* __restrict__ out) {
  __shared__ int2 eds[CAP];   // 12 KB
  __shared__ int cnt[BROWS];
  __shared__ int pos[BROWS];
  __shared__ int cur[BROWS];
  const int b = blockIdx.x;
  const int t = threadIdx.x;
  const int beg = bucket_base[b];
  const int end = bucket_base[b + 1];
  const int n = end - beg;
  const int m = (n < CAP) ? n : CAP;

  if (t < BROWS) cnt[t] = 0;
  __syncthreads();

  for (int i = t; i < m; i += 512)
    atomicAdd(&cnt[((unsigned)bucketed[beg + i].x) >> 24], 1);
  __syncthreads();

  if (t < BROWS) pos[t] = cnt[t];
  __syncthreads();
#pragma unroll
  for (int d = 1; d < BROWS; d <<= 1) {
    int u = 0;
    if (t < BROWS && t >= d) u = pos[t - d];
    __syncthreads();
    if (t < BROWS) pos[t] += u;
    __syncthreads();
  }
  if (t < BROWS) {
    const int excl = pos[t] - cnt[t];
    pos[t] = excl;
    cur[t] = excl;
  }
  __syncthreads();

  for (int i = t; i < m; i += 512) {
    const int2 rec = bucketed[beg + i];
    const int r6 = ((unsigned)rec.x) >> 24;
    const int p = atomicAdd(&cur[r6], 1);
    eds[p] = (int2){rec.x & 0x00FFFFFF, rec.y};
  }
  __syncthreads();

  const int g = t >> 5;          // row group 0..15
  const int lane = t & 31;
  const int j = lane * 4;        // col base

  for (int rr = 0; rr < BROWS / 16; ++rr) {
    const int r = rr * 16 + g;   // interleaved rows for load balance
    const int row = b * BROWS + r;
    const int rbeg = pos[r];
    const int rend = cur[r];

    float a0 = 0.f, a1 = 0.f, a2 = 0.f, a3 = 0.f;
    int e = rbeg;
    for (; e + 3 < rend; e += 4) {
      const int2 p0 = eds[e];
      const int2 p1 = eds[e + 1];
      const int2 p2 = eds[e + 2];
      const int2 p3 = eds[e + 3];
      const ushort4 q0 = *(const ushort4*)(h + (size_t)p0.x * FT + j);
      const ushort4 q1 = *(const ushort4*)(h + (size_t)p1.x * FT + j);
      const ushort4 q2 = *(const ushort4*)(h + (size_t)p2.x * FT + j);
      const ushort4 q3 = *(const ushort4*)(h + (size_t)p3.x * FT + j);
      const float v0 = __int_as_float(p0.y);
      const float v1 = __int_as_float(p1.y);
      const float v2 = __int_as_float(p2.y);
      const float v3 = __int_as_float(p3.y);
      a0 = fmaf(v0, bf2f(q0.x), a0);
      a1 = fmaf(v0, bf2f(q0.y), a1);
      a2 = fmaf(v0, bf2f(q0.z), a2);
      a3 = fmaf(v0, bf2f(q0.w), a3);
      a0 = fmaf(v1, bf2f(q1.x), a0);
      a1 = fmaf(v1, bf2f(q1.y), a1);
      a2 = fmaf(v1, bf2f(q1.z), a2);
      a3 = fmaf(v1, bf2f(q1.w), a3);
      a0 = fmaf(v2, bf2f(q2.x), a0);
      a1 = fmaf(v2, bf2f(q2.y), a1);
      a2 = fmaf(v2, bf2f(q2.z), a2);
      a3 = fmaf(v2, bf2f(q2.w), a3);
      a0 = fmaf(v3, bf2f(q3.x), a0);
      a1 = fmaf(v3, bf2f(q3.y), a1);
      a2 = fmaf(v3, bf2f(q3.z), a2);
      a3 = fmaf(v3, bf2f(q3.w), a3);
    }
    for (; e < rend; ++e) {
      const int2 p0 = eds[e];
      const float v0 = __int_as_float(p0.y);
      const ushort4 q0 = *(const ushort4*)(h + (size_t)p0.x * FT + j);
      a0 = fmaf(v0, bf2f(q0.x), a0);
      a1 = fmaf(v0, bf2f(q0.y), a1);
      a2 = fmaf(v0, bf2f(q0.z), a2);
      a3 = fmaf(v0, bf2f(q0.w), a3);
    }
    if (n > CAP) {  // correctness fallback, statistically never taken
      for (int i = beg + CAP; i < end; ++i) {
        const int2 rec = bucketed[i];
        if ((int)(((unsigned)rec.x) >> 24) == r) {
          const float v0 = __int_as_float(rec.y);
          const ushort4 q0 =
              *(const ushort4*)(h + (size_t)(rec.x & 0x00FFFFFF) * FT + j);
          a0 = fmaf(v0, bf2f(q0.x), a0);
          a1 = fmaf(v0, bf2f(q0.y), a1);
          a2 = fmaf(v0, bf2f(q0.z), a2);
          a3 = fmaf(v0, bf2f(q0.w), a3);
        }
      }
    }

    if (row < N_NODES) {
      float4 o;
      o.x = fmaxf(a0, 0.f);
      o.y = fmaxf(a1, 0.f);
      o.z = fmaxf(a2, 0.f);
      o.w = fmaxf(a3, 0.f);
      *(float4*)(out + (size_t)row * FT + j) = o;
    }
  }
}

// ---------------------------------------------------------------------------
// Fallback (small ws): atomic scatter + relu on bf16 h.
// ---------------------------------------------------------------------------
__global__ __launch_bounds__(256) void edge_scatter_kernel(
    const int* __restrict__ erows,
    const int* __restrict__ ecols,
    const float* __restrict__ evals,
    const ushort* __restrict__ h,
    float* out) {
  const int tid = threadIdx.x;
  const int e = blockIdx.x * 8 + (tid >> 5);
  if (e >= N_EDGES) return;
  const int r = erows[e];
  const int c = ecols[e];
  const float v = evals[e];
  const int j = (tid & 31) * 4;
  const ushort4 q = *(const ushort4*)(h + (size_t)c * FT + j);
  float* op = out + (size_t)r * FT + j;
  atomicAdd(op + 0, v * bf2f(q.x));
  atomicAdd(op + 1, v * bf2f(q.y));
  atomicAdd(op + 2, v * bf2f(q.z));
  atomicAdd(op + 3, v * bf2f(q.w));
}

__global__ __launch_bounds__(256) void relu_kernel(float* out, int n4) {
  const int i = blockIdx.x * blockDim.x + threadIdx.x;
  if (i < n4) {
    float4 v = ((float4*)out)[i];
    v.x = fmaxf(v.x, 0.f);
    v.y = fmaxf(v.y, 0.f);
    v.z = fmaxf(v.z, 0.f);
    v.w = fmaxf(v.w, 0.f);
    ((float4*)out)[i] = v;
  }
}

extern "C" void kernel_launch(void* const* d_in, const int* in_sizes, int n_in,
                              void* d_out, int out_size, void* d_ws, size_t ws_size,
                              hipStream_t stream) {
  const float* x = (const float*)d_in[0];
  const int* erows = (const int*)d_in[1];
  const int* ecols = (const int*)d_in[2];
  const float* evals = (const float*)d_in[3];
  const float* W = (const float*)d_in[4];
  const float* b = (const float*)d_in[5];
  float* out = (float*)d_out;

  char* ws = (char*)d_ws;
  ushort* h = (ushort*)(ws + OFF_H);

  gemm_bias_kernel<<<(N_NODES + 255) / 256, 256, 0, stream>>>(x, W, b, h);

  if (ws_size >= (size_t)WS_NEEDED) {
    int2* bucketed = (int2*)(ws + OFF_BUCKETED);
    int* blkhist = (int*)(ws + OFF_BLKHIST);
    int* btot = (int*)(ws + OFF_BTOT);
    int* bucket_base = (int*)(ws + OFF_BBASE);

    partA_kernel<<<NBLKP, 256, 0, stream>>>(erows, blkhist);
    partB1_kernel<<<(NBUCK + B1TILE - 1) / B1TILE, 512, 0, stream>>>(blkhist,
                                                                     btot);
    partB2_kernel<<<1, 512, 0, stream>>>(btot, bucket_base);
    partC_kernel<<<NBLKP, 256, 0, stream>>>(erows, ecols, evals, blkhist,
                                            bucket_base, bucketed);
    spmm_bucket_kernel<<<NBUCK, 512, 0, stream>>>(bucketed, bucket_base, h,
                                                  out);
  } else {
    hipMemsetAsync(d_out, 0, (size_t)out_size * sizeof(float), stream);
    edge_scatter_kernel<<<(N_EDGES + 7) / 8, 256, 0, stream>>>(erows, ecols,
                                                               evals, h, out);
    const int n4 = out_size / 4;
    relu_kernel<<<(n4 + 255) / 256, 256, 0, stream>>>(out, n4);
  }
}

// Round 16
// 123.338 us; speedup vs baseline: 1.2525x; 1.1106x over previous
//
#include <hip/hip_runtime.h>

#define N_NODES 100000
#define N_EDGES 1600000
#define FT 128

#define NBUCK 391   // partition buckets: 256 rows each (row >> 8)
#define EPB 4096    // edges per partition block
#define NBLKP ((N_EDGES + EPB - 1) / EPB)  // 391 partition blocks
#define CAP 1536    // staged edges per 64-row quarter (avg 1023, +16 sigma)

// ---- workspace layout (bytes) ----------------------------------------------
// h_bf        [0,           25,600,000)   N_NODES*FT*2 (bf16)
// bucketed    [25,600,000,  38,400,000)   N_EDGES int2 (packed row8|col, val)
// blkhist     [38,400,000,  39,011,524)   NBLKP*NBUCK ints (block-major)
// btot        [39,011,524,  39,013,088)   NBUCK ints
// bucket_base [39,013,088,  39,014,656)   NBUCK+1 ints
#define OFF_H 0
#define OFF_BUCKETED 25600000
#define OFF_BLKHIST 38400000
#define OFF_BTOT 39011524
#define OFF_BBASE 39013088
#define WS_NEEDED 39014656

typedef __attribute__((ext_vector_type(8))) short bf16x8;
typedef __attribute__((ext_vector_type(4))) float f32x4;

// bf16 helpers (RNE pack, shift-unpack).
static __device__ __forceinline__ ushort f2bf(float f) {
  const unsigned u = __float_as_uint(f);
  return (ushort)((u + 0x7FFF + ((u >> 16) & 1)) >> 16);
}
static __device__ __forceinline__ float bf2f(ushort s) {
  return __uint_as_float((unsigned)s << 16);
}

// ---------------------------------------------------------------------------
// Kernel 1: dense projection  h = x @ W + b  (bf16 output) via MFMA.
// ---------------------------------------------------------------------------
__global__ __launch_bounds__(256) void gemm_bias_kernel(
    const float* __restrict__ x,
    const float* __restrict__ W,
    const float* __restrict__ b,
    ushort* __restrict__ h) {
  __shared__ __align__(16) ushort whi[16384];
  __shared__ __align__(16) ushort wlo[16384];

  const int tid = threadIdx.x;

  for (int idx = tid; idx < 16384; idx += 256) {
    const int k = idx >> 7;
    const int col = idx & 127;
    const float wv = W[idx];
    const ushort hi = f2bf(wv);
    const ushort lo = f2bf(wv - bf2f(hi));
    const int lane_ = (((k >> 3) & 3) << 4) | (col & 15);
    const int pos = ((((k >> 5) << 3) + (col >> 4)) * 64 + lane_) * 8 + (k & 7);
    whi[pos] = hi;
    wlo[pos] = lo;
  }
  __syncthreads();

  const int w = tid >> 6;
  const int lane = tid & 63;
  const int r0 = blockIdx.x * 256 + w * 64;
  const int arow = lane & 15;
  const int kgrp = (lane >> 4) << 3;

  float bias_v[8];
#pragma unroll
  for (int ct = 0; ct < 8; ++ct) bias_v[ct] = b[ct * 16 + (lane & 15)];

  f32x4 acc[4][8];
#pragma unroll
  for (int rf = 0; rf < 4; ++rf)
#pragma unroll
    for (int ct = 0; ct < 8; ++ct) acc[rf][ct] = (f32x4){0.f, 0.f, 0.f, 0.f};

#pragma unroll
  for (int ks = 0; ks < 4; ++ks) {
    bf16x8 afr[4];
#pragma unroll
    for (int rf = 0; rf < 4; ++rf) {
      int r = r0 + rf * 16 + arow;
      r = (r < N_NODES) ? r : (N_NODES - 1);
      const float* xp = x + (size_t)r * FT + ks * 32 + kgrp;
      const float4 u0 = *(const float4*)xp;
      const float4 u1 = *(const float4*)(xp + 4);
      bf16x8 a;
      a[0] = (short)f2bf(u0.x);
      a[1] = (short)f2bf(u0.y);
      a[2] = (short)f2bf(u0.z);
      a[3] = (short)f2bf(u0.w);
      a[4] = (short)f2bf(u1.x);
      a[5] = (short)f2bf(u1.y);
      a[6] = (short)f2bf(u1.z);
      a[7] = (short)f2bf(u1.w);
      afr[rf] = a;
    }
#pragma unroll
    for (int ct = 0; ct < 8; ++ct) {
      const int fo = ((ks * 8 + ct) * 64 + lane) * 8;
      const bf16x8 bh = *(const bf16x8*)&whi[fo];
      const bf16x8 bl = *(const bf16x8*)&wlo[fo];
#pragma unroll
      for (int rf = 0; rf < 4; ++rf) {
        acc[rf][ct] = __builtin_amdgcn_mfma_f32_16x16x32_bf16(
            afr[rf], bh, acc[rf][ct], 0, 0, 0);
        acc[rf][ct] = __builtin_amdgcn_mfma_f32_16x16x32_bf16(
            afr[rf], bl, acc[rf][ct], 0, 0, 0);
      }
    }
  }

  const int crow0 = (lane >> 4) << 2;
  const int ccol = lane & 15;
#pragma unroll
  for (int rf = 0; rf < 4; ++rf) {
#pragma unroll
    for (int ct = 0; ct < 8; ++ct) {
      const int col = ct * 16 + ccol;
#pragma unroll
      for (int i = 0; i < 4; ++i) {
        const int row = r0 + rf * 16 + crow0 + i;
        if (row < N_NODES)
          h[(size_t)row * FT + col] = f2bf(acc[rf][ct][i] + bias_v[ct]);
      }
    }
  }
}

// ---------------------------------------------------------------------------
// Pass A: per-block LDS histogram over 256-row buckets.
// ---------------------------------------------------------------------------
__global__ __launch_bounds__(256) void partA_kernel(
    const int* __restrict__ erows, int* __restrict__ blkhist) {
  __shared__ int cnt[NBUCK];
  const int tid = threadIdx.x;
  for (int j = tid; j < NBUCK; j += 256) cnt[j] = 0;
  __syncthreads();

  const int base4 = blockIdx.x * (EPB / 4);
#pragma unroll
  for (int it = 0; it < EPB / 4 / 256; ++it) {
    const int idx4 = base4 + it * 256 + tid;
    if (idx4 < N_EDGES / 4) {
      const int4 r = ((const int4*)erows)[idx4];
      atomicAdd(&cnt[r.x >> 8], 1);
      atomicAdd(&cnt[r.y >> 8], 1);
      atomicAdd(&cnt[r.z >> 8], 1);
      atomicAdd(&cnt[r.w >> 8], 1);
    }
  }
  __syncthreads();
  int* dst = blkhist + (size_t)blockIdx.x * NBUCK;
  for (int j = tid; j < NBUCK; j += 256) dst[j] = cnt[j];
}

// ---------------------------------------------------------------------------
// Pass B1: per-bucket Hillis-Steele scan over partition blocks (grid=NBUCK,
// massively parallel; 391 scattered loads per block but 1563*512... here
// 391 blocks x 512 threads — the R12 version that measured fast).
// ---------------------------------------------------------------------------
__global__ __launch_bounds__(512) void partB1_kernel(
    int* __restrict__ blkhist, int* __restrict__ btot) {
  __shared__ int ps[512];
  const int b = blockIdx.x;
  const int t = threadIdx.x;
  int v = 0;
  if (t < NBLKP) v = blkhist[(size_t)t * NBUCK + b];
  ps[t] = v;
  __syncthreads();
#pragma unroll
  for (int d = 1; d < 512; d <<= 1) {
    const int u = (t >= d) ? ps[t - d] : 0;
    __syncthreads();
    ps[t] += u;
    __syncthreads();
  }
  if (t < NBLKP) blkhist[(size_t)t * NBUCK + b] = ps[t] - v;  // exclusive
  if (t == NBLKP - 1) btot[b] = ps[t];
}

// ---------------------------------------------------------------------------
// Pass B2: exclusive-scan btot -> bucket_base (+ sentinel).
// ---------------------------------------------------------------------------
__global__ __launch_bounds__(512) void partB2_kernel(
    const int* __restrict__ btot, int* __restrict__ bucket_base) {
  __shared__ int ps[512];
  const int t = threadIdx.x;
  int v = (t < NBUCK) ? btot[t] : 0;
  ps[t] = v;
  __syncthreads();
#pragma unroll
  for (int d = 1; d < 512; d <<= 1) {
    const int u = (t >= d) ? ps[t - d] : 0;
    __syncthreads();
    ps[t] += u;
    __syncthreads();
  }
  if (t < NBUCK) bucket_base[t] = ps[t] - v;
  if (t == NBUCK - 1) bucket_base[NBUCK] = N_EDGES;
}

// ---------------------------------------------------------------------------
// Pass C: partition scatter into 256-row bucket regions; pack row&255.
// ---------------------------------------------------------------------------
__global__ __launch_bounds__(256) void partC_kernel(
    const int* __restrict__ erows,
    const int* __restrict__ ecols,
    const float* __restrict__ evals,
    const int* __restrict__ blkhist,
    const int* __restrict__ bucket_base,
    int2* __restrict__ bucketed) {
  __shared__ int cur[NBUCK];
  const int tid = threadIdx.x;
  const int* src = blkhist + (size_t)blockIdx.x * NBUCK;
  for (int j = tid; j < NBUCK; j += 256) cur[j] = src[j] + bucket_base[j];
  __syncthreads();

  const int base4 = blockIdx.x * (EPB / 4);
#pragma unroll
  for (int it = 0; it < EPB / 4 / 256; ++it) {
    const int idx4 = base4 + it * 256 + tid;
    if (idx4 < N_EDGES / 4) {
      const int4 r = ((const int4*)erows)[idx4];
      const int4 c = ((const int4*)ecols)[idx4];
      const float4 v = ((const float4*)evals)[idx4];
      int p;
      p = atomicAdd(&cur[r.x >> 8], 1);
      bucketed[p] = (int2){((r.x & 255) << 24) | c.x, __float_as_int(v.x)};
      p = atomicAdd(&cur[r.y >> 8], 1);
      bucketed[p] = (int2){((r.y & 255) << 24) | c.y, __float_as_int(v.y)};
      p = atomicAdd(&cur[r.z >> 8], 1);
      bucketed[p] = (int2){((r.z & 255) << 24) | c.z, __float_as_int(v.z)};
      p = atomicAdd(&cur[r.w >> 8], 1);
      bucketed[p] = (int2){((r.w & 255) << 24) | c.w, __float_as_int(v.w)};
    }
  }
}

// ---------------------------------------------------------------------------
// Fused filter + sort + SpMM: grid = NBUCK*4. Block (b,q) handles quarter q
// (64 rows) of bucket b: single pass over the bucket region filters its
// quarter's edges into tmp (unsorted) while histogramming; scan; LDS->LDS
// counting sort into eds; per-row gather+FMA+ReLU; one out write.
// LDS ~25KB, 512 threads -> 4 blocks/CU (thread-capped) = full occupancy.
// ---------------------------------------------------------------------------
__global__ __launch_bounds__(512) void spmm_bucket_kernel(
    const int2* __restrict__ bucketed,
    const int* __restrict__ bucket_base,
    const ushort* __restrict__ h,
    float* __restrict__ out) {
  __shared__ int2 tmp[CAP];   // 12 KB unsorted stage
  __shared__ int2 eds[CAP];   // 12 KB sorted
  __shared__ int cnt[64];
  __shared__ int pos[64];
  __shared__ int cur[64];
  __shared__ int ns;
  const int b = blockIdx.x >> 2;
  const int q = blockIdx.x & 3;
  const int t = threadIdx.x;
  const int beg = bucket_base[b];
  const int end = bucket_base[b + 1];

  if (t < 64) cnt[t] = 0;
  if (t == 0) ns = 0;
  __syncthreads();

  // Filtered staging: keep records whose 64-row quarter matches q.
  for (int i = beg + t; i < end; i += 512) {
    const int2 rec = bucketed[i];
    const int r8 = ((unsigned)rec.x) >> 24;
    if ((r8 >> 6) == q) {
      const int p = atomicAdd(&ns, 1);
      if (p < CAP) {
        tmp[p] = rec;
        atomicAdd(&cnt[r8 & 63], 1);
      }
    }
  }
  __syncthreads();

  const int m = (ns < CAP) ? ns : CAP;
  const bool overflow = (ns > CAP);

  if (t < 64) pos[t] = cnt[t];
  __syncthreads();
#pragma unroll
  for (int d = 1; d < 64; d <<= 1) {
    int u = 0;
    if (t < 64 && t >= d) u = pos[t - d];
    __syncthreads();
    if (t < 64) pos[t] += u;
    __syncthreads();
  }
  if (t < 64) {
    const int excl = pos[t] - cnt[t];
    pos[t] = excl;
    cur[t] = excl;
  }
  __syncthreads();

  // LDS -> LDS counting sort.
  for (int i = t; i < m; i += 512) {
    const int2 rec = tmp[i];
    const int r6 = (((unsigned)rec.x) >> 24) & 63;
    const int p = atomicAdd(&cur[r6], 1);
    eds[p] = (int2){rec.x & 0x00FFFFFF, rec.y};
  }
  __syncthreads();

  const int g = t >> 5;          // row group 0..15
  const int lane = t & 31;
  const int j = lane * 4;        // col base

  for (int rr = 0; rr < 4; ++rr) {
    const int r = rr * 16 + g;   // row within quarter, interleaved
    const int row = b * 256 + q * 64 + r;
    const int rbeg = pos[r];
    const int rend = cur[r];

    float a0 = 0.f, a1 = 0.f, a2 = 0.f, a3 = 0.f;
    int e = rbeg;
    for (; e + 3 < rend; e += 4) {
      const int2 p0 = eds[e];
      const int2 p1 = eds[e + 1];
      const int2 p2 = eds[e + 2];
      const int2 p3 = eds[e + 3];
      const ushort4 q0 = *(const ushort4*)(h + (size_t)p0.x * FT + j);
      const ushort4 q1 = *(const ushort4*)(h + (size_t)p1.x * FT + j);
      const ushort4 q2 = *(const ushort4*)(h + (size_t)p2.x * FT + j);
      const ushort4 q3 = *(const ushort4*)(h + (size_t)p3.x * FT + j);
      const float v0 = __int_as_float(p0.y);
      const float v1 = __int_as_float(p1.y);
      const float v2 = __int_as_float(p2.y);
      const float v3 = __int_as_float(p3.y);
      a0 = fmaf(v0, bf2f(q0.x), a0);
      a1 = fmaf(v0, bf2f(q0.y), a1);
      a2 = fmaf(v0, bf2f(q0.z), a2);
      a3 = fmaf(v0, bf2f(q0.w), a3);
      a0 = fmaf(v1, bf2f(q1.x), a0);
      a1 = fmaf(v1, bf2f(q1.y), a1);
      a2 = fmaf(v1, bf2f(q1.z), a2);
      a3 = fmaf(v1, bf2f(q1.w), a3);
      a0 = fmaf(v2, bf2f(q2.x), a0);
      a1 = fmaf(v2, bf2f(q2.y), a1);
      a2 = fmaf(v2, bf2f(q2.z), a2);
      a3 = fmaf(v2, bf2f(q2.w), a3);
      a0 = fmaf(v3, bf2f(q3.x), a0);
      a1 = fmaf(v3, bf2f(q3.y), a1);
      a2 = fmaf(v3, bf2f(q3.z), a2);
      a3 = fmaf(v3, bf2f(q3.w), a3);
    }
    for (; e < rend; ++e) {
      const int2 p0 = eds[e];
      const float v0 = __int_as_float(p0.y);
      const ushort4 q0 = *(const ushort4*)(h + (size_t)p0.x * FT + j);
      a0 = fmaf(v0, bf2f(q0.x), a0);
      a1 = fmaf(v0, bf2f(q0.y), a1);
      a2 = fmaf(v0, bf2f(q0.z), a2);
      a3 = fmaf(v0, bf2f(q0.w), a3);
    }
    if (overflow) {  // correctness fallback: rescan region from global
      // Records beyond the first CAP staged for this quarter were dropped;
      // recover by scanning the bucket region and processing this row's
      // edges that did not make it into tmp. Count staged occurrences to
      // know how many leading matches were handled.
      int seen = 0;
      const int have = rend - rbeg;
      for (int i = beg; i < end; ++i) {
        const int2 rec = bucketed[i];
        const int r8 = ((unsigned)rec.x) >> 24;
        if ((r8 >> 6) == q && (r8 & 63) == r) {
          ++seen;
          if (seen > have) {
            const float v0 = __int_as_float(rec.y);
            const ushort4 q0 =
                *(const ushort4*)(h + (size_t)(rec.x & 0x00FFFFFF) * FT + j);
            a0 = fmaf(v0, bf2f(q0.x), a0);
            a1 = fmaf(v0, bf2f(q0.y), a1);
            a2 = fmaf(v0, bf2f(q0.z), a2);
            a3 = fmaf(v0, bf2f(q0.w), a3);
          }
        }
      }
    }

    if (row < N_NODES) {
      float4 o;
      o.x = fmaxf(a0, 0.f);
      o.y = fmaxf(a1, 0.f);
      o.z = fmaxf(a2, 0.f);
      o.w = fmaxf(a3, 0.f);
      *(float4*)(out + (size_t)row * FT + j) = o;
    }
  }
}

// ---------------------------------------------------------------------------
// Fallback (small ws): atomic scatter + relu on bf16 h.
// ---------------------------------------------------------------------------
__global__ __launch_bounds__(256) void edge_scatter_kernel(
    const int* __restrict__ erows,
    const int* __restrict__ ecols,
    const float* __restrict__ evals,
    const ushort* __restrict__ h,
    float* out) {
  const int tid = threadIdx.x;
  const int e = blockIdx.x * 8 + (tid >> 5);
  if (e >= N_EDGES) return;
  const int r = erows[e];
  const int c = ecols[e];
  const float v = evals[e];
  const int j = (tid & 31) * 4;
  const ushort4 q = *(const ushort4*)(h + (size_t)c * FT + j);
  float* op = out + (size_t)r * FT + j;
  atomicAdd(op + 0, v * bf2f(q.x));
  atomicAdd(op + 1, v * bf2f(q.y));
  atomicAdd(op + 2, v * bf2f(q.z));
  atomicAdd(op + 3, v * bf2f(q.w));
}

__global__ __launch_bounds__(256) void relu_kernel(float* out, int n4) {
  const int i = blockIdx.x * blockDim.x + threadIdx.x;
  if (i < n4) {
    float4 v = ((float4*)out)[i];
    v.x = fmaxf(v.x, 0.f);
    v.y = fmaxf(v.y, 0.f);
    v.z = fmaxf(v.z, 0.f);
    v.w = fmaxf(v.w, 0.f);
    ((float4*)out)[i] = v;
  }
}

extern "C" void kernel_launch(void* const* d_in, const int* in_sizes, int n_in,
                              void* d_out, int out_size, void* d_ws, size_t ws_size,
                              hipStream_t stream) {
  const float* x = (const float*)d_in[0];
  const int* erows = (const int*)d_in[1];
  const int* ecols = (const int*)d_in[2];
  const float* evals = (const float*)d_in[3];
  const float* W = (const float*)d_in[4];
  const float* b = (const float*)d_in[5];
  float* out = (float*)d_out;

  char* ws = (char*)d_ws;
  ushort* h = (ushort*)(ws + OFF_H);

  gemm_bias_kernel<<<(N_NODES + 255) / 256, 256, 0, stream>>>(x, W, b, h);

  if (ws_size >= (size_t)WS_NEEDED) {
    int2* bucketed = (int2*)(ws + OFF_BUCKETED);
    int* blkhist = (int*)(ws + OFF_BLKHIST);
    int* btot = (int*)(ws + OFF_BTOT);
    int* bucket_base = (int*)(ws + OFF_BBASE);

    partA_kernel<<<NBLKP, 256, 0, stream>>>(erows, blkhist);
    partB1_kernel<<<NBUCK, 512, 0, stream>>>(blkhist, btot);
    partB2_kernel<<<1, 512, 0, stream>>>(btot, bucket_base);
    partC_kernel<<<NBLKP, 256, 0, stream>>>(erows, ecols, evals, blkhist,
                                            bucket_base, bucketed);
    spmm_bucket_kernel<<<NBUCK * 4, 512, 0, stream>>>(bucketed, bucket_base,
                                                      h, out);
  } else {
    hipMemsetAsync(d_out, 0, (size_t)out_size * sizeof(float), stream);
    edge_scatter_kernel<<<(N_EDGES + 7) / 8, 256, 0, stream>>>(erows, ecols,
                                                               evals, h, out);
    const int n4 = out_size / 4;
    relu_kernel<<<(n4 + 255) / 256, 256, 0, stream>>>(out, n4);
  }
}

// Round 17
// 117.779 us; speedup vs baseline: 1.3116x; 1.0472x over previous
//
#include <hip/hip_runtime.h>

#define N_NODES 100000
#define N_EDGES 1600000
#define FT 128

#define NBUCK 391   // partition buckets: 256 rows each (row >> 8)
#define EPB 4096    // edges per partition block
#define NBLKP ((N_EDGES + EPB - 1) / EPB)  // 391 partition blocks
#define CAP 1536    // staged edges per 64-row quarter (avg 1023, +16 sigma)
#define GEMM_BLOCKS ((N_NODES + 255) / 256)  // 391

// ---- workspace layout (bytes) ----------------------------------------------
// h_bf        [0,           25,600,000)   N_NODES*FT*2 (bf16)
// bucketed    [25,600,000,  38,400,000)   N_EDGES int2 (packed row8|col, val)
// blkhist     [38,400,000,  39,011,524)   NBLKP*NBUCK ints (block-major)
// btot        [39,011,524,  39,013,088)   NBUCK ints
// bucket_base [39,013,088,  39,014,656)   NBUCK+1 ints
#define OFF_H 0
#define OFF_BUCKETED 25600000
#define OFF_BLKHIST 38400000
#define OFF_BTOT 39011524
#define OFF_BBASE 39013088
#define WS_NEEDED 39014656

typedef __attribute__((ext_vector_type(8))) short bf16x8;
typedef __attribute__((ext_vector_type(4))) float f32x4;

// bf16 helpers (RNE pack, shift-unpack).
static __device__ __forceinline__ ushort f2bf(float f) {
  const unsigned u = __float_as_uint(f);
  return (ushort)((u + 0x7FFF + ((u >> 16) & 1)) >> 16);
}
static __device__ __forceinline__ float bf2f(ushort s) {
  return __uint_as_float((unsigned)s << 16);
}

// ---------------------------------------------------------------------------
// Pass A: per-block LDS histogram over 256-row buckets.
// ---------------------------------------------------------------------------
__global__ __launch_bounds__(256) void partA_kernel(
    const int* __restrict__ erows, int* __restrict__ blkhist) {
  __shared__ int cnt[NBUCK];
  const int tid = threadIdx.x;
  for (int j = tid; j < NBUCK; j += 256) cnt[j] = 0;
  __syncthreads();

  const int base4 = blockIdx.x * (EPB / 4);
#pragma unroll
  for (int it = 0; it < EPB / 4 / 256; ++it) {
    const int idx4 = base4 + it * 256 + tid;
    if (idx4 < N_EDGES / 4) {
      const int4 r = ((const int4*)erows)[idx4];
      atomicAdd(&cnt[r.x >> 8], 1);
      atomicAdd(&cnt[r.y >> 8], 1);
      atomicAdd(&cnt[r.z >> 8], 1);
      atomicAdd(&cnt[r.w >> 8], 1);
    }
  }
  __syncthreads();
  int* dst = blkhist + (size_t)blockIdx.x * NBUCK;
  for (int j = tid; j < NBUCK; j += 256) dst[j] = cnt[j];
}

// ---------------------------------------------------------------------------
// Pass B1: per-bucket Hillis-Steele scan over partition blocks (grid=NBUCK).
// ---------------------------------------------------------------------------
__global__ __launch_bounds__(512) void partB1_kernel(
    int* __restrict__ blkhist, int* __restrict__ btot) {
  __shared__ int ps[512];
  const int b = blockIdx.x;
  const int t = threadIdx.x;
  int v = 0;
  if (t < NBLKP) v = blkhist[(size_t)t * NBUCK + b];
  ps[t] = v;
  __syncthreads();
#pragma unroll
  for (int d = 1; d < 512; d <<= 1) {
    const int u = (t >= d) ? ps[t - d] : 0;
    __syncthreads();
    ps[t] += u;
    __syncthreads();
  }
  if (t < NBLKP) blkhist[(size_t)t * NBUCK + b] = ps[t] - v;  // exclusive
  if (t == NBLKP - 1) btot[b] = ps[t];
}

// ---------------------------------------------------------------------------
// Pass B2: exclusive-scan btot -> bucket_base (+ sentinel).
// ---------------------------------------------------------------------------
__global__ __launch_bounds__(512) void partB2_kernel(
    const int* __restrict__ btot, int* __restrict__ bucket_base) {
  __shared__ int ps[512];
  const int t = threadIdx.x;
  int v = (t < NBUCK) ? btot[t] : 0;
  ps[t] = v;
  __syncthreads();
#pragma unroll
  for (int d = 1; d < 512; d <<= 1) {
    const int u = (t >= d) ? ps[t - d] : 0;
    __syncthreads();
    ps[t] += u;
    __syncthreads();
  }
  if (t < NBUCK) bucket_base[t] = ps[t] - v;
  if (t == NBUCK - 1) bucket_base[NBUCK] = N_EDGES;
}

// ---------------------------------------------------------------------------
// FUSED gemm + partC: grid = GEMM_BLOCKS + NBLKP; blocks < GEMM_BLOCKS run
// the MFMA projection (h = x@W + b, bf16 out, single-precision-W-as-bf16 —
// W-lo correction dropped: its contribution (~1.4e-3) is far below the
// existing bf16-h storage error (~5e-3)); remaining blocks run the partition
// scatter. gemm is independent of the sort chain, so its ~12us hides under
// partC's scattered-write-bound ~20us. LDS = 32KB(W) + 1.6KB(cur) ->
// 4 blocks/CU for both halves.
// ---------------------------------------------------------------------------
__global__ __launch_bounds__(256) void fused_gemm_partC_kernel(
    const float* __restrict__ x,
    const float* __restrict__ W,
    const float* __restrict__ b,
    ushort* __restrict__ h,
    const int* __restrict__ erows,
    const int* __restrict__ ecols,
    const float* __restrict__ evals,
    const int* __restrict__ blkhist,
    const int* __restrict__ bucket_base,
    int2* __restrict__ bucketed) {
  __shared__ __align__(16) ushort whi[16384];  // 32 KB (gemm half)
  __shared__ int cur[NBUCK];                   // 1.6 KB (partC half)
  const int tid = threadIdx.x;

  if (blockIdx.x < GEMM_BLOCKS) {
    // ------------------------- gemm half ---------------------------------
    for (int idx = tid; idx < 16384; idx += 256) {
      const int k = idx >> 7;
      const int col = idx & 127;
      const ushort hi = f2bf(W[idx]);
      const int lane_ = (((k >> 3) & 3) << 4) | (col & 15);
      const int pos =
          ((((k >> 5) << 3) + (col >> 4)) * 64 + lane_) * 8 + (k & 7);
      whi[pos] = hi;
    }
    __syncthreads();

    const int w = tid >> 6;
    const int lane = tid & 63;
    const int r0 = blockIdx.x * 256 + w * 64;
    const int arow = lane & 15;
    const int kgrp = (lane >> 4) << 3;

    float bias_v[8];
#pragma unroll
    for (int ct = 0; ct < 8; ++ct) bias_v[ct] = b[ct * 16 + (lane & 15)];

    f32x4 acc[4][8];
#pragma unroll
    for (int rf = 0; rf < 4; ++rf)
#pragma unroll
      for (int ct = 0; ct < 8; ++ct) acc[rf][ct] = (f32x4){0.f, 0.f, 0.f, 0.f};

#pragma unroll
    for (int ks = 0; ks < 4; ++ks) {
      bf16x8 afr[4];
#pragma unroll
      for (int rf = 0; rf < 4; ++rf) {
        int r = r0 + rf * 16 + arow;
        r = (r < N_NODES) ? r : (N_NODES - 1);
        const float* xp = x + (size_t)r * FT + ks * 32 + kgrp;
        const float4 u0 = *(const float4*)xp;
        const float4 u1 = *(const float4*)(xp + 4);
        bf16x8 a;
        a[0] = (short)f2bf(u0.x);
        a[1] = (short)f2bf(u0.y);
        a[2] = (short)f2bf(u0.z);
        a[3] = (short)f2bf(u0.w);
        a[4] = (short)f2bf(u1.x);
        a[5] = (short)f2bf(u1.y);
        a[6] = (short)f2bf(u1.z);
        a[7] = (short)f2bf(u1.w);
        afr[rf] = a;
      }
#pragma unroll
      for (int ct = 0; ct < 8; ++ct) {
        const int fo = ((ks * 8 + ct) * 64 + lane) * 8;
        const bf16x8 bh = *(const bf16x8*)&whi[fo];
#pragma unroll
        for (int rf = 0; rf < 4; ++rf) {
          acc[rf][ct] = __builtin_amdgcn_mfma_f32_16x16x32_bf16(
              afr[rf], bh, acc[rf][ct], 0, 0, 0);
        }
      }
    }

    const int crow0 = (lane >> 4) << 2;
    const int ccol = lane & 15;
#pragma unroll
    for (int rf = 0; rf < 4; ++rf) {
#pragma unroll
      for (int ct = 0; ct < 8; ++ct) {
        const int col = ct * 16 + ccol;
#pragma unroll
        for (int i = 0; i < 4; ++i) {
          const int row = r0 + rf * 16 + crow0 + i;
          if (row < N_NODES)
            h[(size_t)row * FT + col] = f2bf(acc[rf][ct][i] + bias_v[ct]);
        }
      }
    }
  } else {
    // ------------------------- partC half --------------------------------
    const int bid = blockIdx.x - GEMM_BLOCKS;
    const int* src = blkhist + (size_t)bid * NBUCK;
    for (int j = tid; j < NBUCK; j += 256) cur[j] = src[j] + bucket_base[j];
    __syncthreads();

    const int base4 = bid * (EPB / 4);
#pragma unroll
    for (int it = 0; it < EPB / 4 / 256; ++it) {
      const int idx4 = base4 + it * 256 + tid;
      if (idx4 < N_EDGES / 4) {
        const int4 r = ((const int4*)erows)[idx4];
        const int4 c = ((const int4*)ecols)[idx4];
        const float4 v = ((const float4*)evals)[idx4];
        int p;
        p = atomicAdd(&cur[r.x >> 8], 1);
        bucketed[p] = (int2){((r.x & 255) << 24) | c.x, __float_as_int(v.x)};
        p = atomicAdd(&cur[r.y >> 8], 1);
        bucketed[p] = (int2){((r.y & 255) << 24) | c.y, __float_as_int(v.y)};
        p = atomicAdd(&cur[r.z >> 8], 1);
        bucketed[p] = (int2){((r.z & 255) << 24) | c.z, __float_as_int(v.z)};
        p = atomicAdd(&cur[r.w >> 8], 1);
        bucketed[p] = (int2){((r.w & 255) << 24) | c.w, __float_as_int(v.w)};
      }
    }
  }
}

// ---------------------------------------------------------------------------
// Fused filter + sort + SpMM: grid = NBUCK*4. Block (b,q) handles quarter q
// (64 rows) of bucket b (unchanged from R16).
// ---------------------------------------------------------------------------
__global__ __launch_bounds__(512) void spmm_bucket_kernel(
    const int2* __restrict__ bucketed,
    const int* __restrict__ bucket_base,
    const ushort* __restrict__ h,
    float* __restrict__ out) {
  __shared__ int2 tmp[CAP];   // 12 KB unsorted stage
  __shared__ int2 eds[CAP];   // 12 KB sorted
  __shared__ int cnt[64];
  __shared__ int pos[64];
  __shared__ int cur[64];
  __shared__ int ns;
  const int b = blockIdx.x >> 2;
  const int q = blockIdx.x & 3;
  const int t = threadIdx.x;
  const int beg = bucket_base[b];
  const int end = bucket_base[b + 1];

  if (t < 64) cnt[t] = 0;
  if (t == 0) ns = 0;
  __syncthreads();

  for (int i = beg + t; i < end; i += 512) {
    const int2 rec = bucketed[i];
    const int r8 = ((unsigned)rec.x) >> 24;
    if ((r8 >> 6) == q) {
      const int p = atomicAdd(&ns, 1);
      if (p < CAP) {
        tmp[p] = rec;
        atomicAdd(&cnt[r8 & 63], 1);
      }
    }
  }
  __syncthreads();

  const int m = (ns < CAP) ? ns : CAP;
  const bool overflow = (ns > CAP);

  if (t < 64) pos[t] = cnt[t];
  __syncthreads();
#pragma unroll
  for (int d = 1; d < 64; d <<= 1) {
    int u = 0;
    if (t < 64 && t >= d) u = pos[t - d];
    __syncthreads();
    if (t < 64) pos[t] += u;
    __syncthreads();
  }
  if (t < 64) {
    const int excl = pos[t] - cnt[t];
    pos[t] = excl;
    cur[t] = excl;
  }
  __syncthreads();

  for (int i = t; i < m; i += 512) {
    const int2 rec = tmp[i];
    const int r6 = (((unsigned)rec.x) >> 24) & 63;
    const int p = atomicAdd(&cur[r6], 1);
    eds[p] = (int2){rec.x & 0x00FFFFFF, rec.y};
  }
  __syncthreads();

  const int g = t >> 5;
  const int lane = t & 31;
  const int j = lane * 4;

  for (int rr = 0; rr < 4; ++rr) {
    const int r = rr * 16 + g;
    const int row = b * 256 + q * 64 + r;
    const int rbeg = pos[r];
    const int rend = cur[r];

    float a0 = 0.f, a1 = 0.f, a2 = 0.f, a3 = 0.f;
    int e = rbeg;
    for (; e + 3 < rend; e += 4) {
      const int2 p0 = eds[e];
      const int2 p1 = eds[e + 1];
      const int2 p2 = eds[e + 2];
      const int2 p3 = eds[e + 3];
      const ushort4 q0 = *(const ushort4*)(h + (size_t)p0.x * FT + j);
      const ushort4 q1 = *(const ushort4*)(h + (size_t)p1.x * FT + j);
      const ushort4 q2 = *(const ushort4*)(h + (size_t)p2.x * FT + j);
      const ushort4 q3 = *(const ushort4*)(h + (size_t)p3.x * FT + j);
      const float v0 = __int_as_float(p0.y);
      const float v1 = __int_as_float(p1.y);
      const float v2 = __int_as_float(p2.y);
      const float v3 = __int_as_float(p3.y);
      a0 = fmaf(v0, bf2f(q0.x), a0);
      a1 = fmaf(v0, bf2f(q0.y), a1);
      a2 = fmaf(v0, bf2f(q0.z), a2);
      a3 = fmaf(v0, bf2f(q0.w), a3);
      a0 = fmaf(v1, bf2f(q1.x), a0);
      a1 = fmaf(v1, bf2f(q1.y), a1);
      a2 = fmaf(v1, bf2f(q1.z), a2);
      a3 = fmaf(v1, bf2f(q1.w), a3);
      a0 = fmaf(v2, bf2f(q2.x), a0);
      a1 = fmaf(v2, bf2f(q2.y), a1);
      a2 = fmaf(v2, bf2f(q2.z), a2);
      a3 = fmaf(v2, bf2f(q2.w), a3);
      a0 = fmaf(v3, bf2f(q3.x), a0);
      a1 = fmaf(v3, bf2f(q3.y), a1);
      a2 = fmaf(v3, bf2f(q3.z), a2);
      a3 = fmaf(v3, bf2f(q3.w), a3);
    }
    for (; e < rend; ++e) {
      const int2 p0 = eds[e];
      const float v0 = __int_as_float(p0.y);
      const ushort4 q0 = *(const ushort4*)(h + (size_t)p0.x * FT + j);
      a0 = fmaf(v0, bf2f(q0.x), a0);
      a1 = fmaf(v0, bf2f(q0.y), a1);
      a2 = fmaf(v0, bf2f(q0.z), a2);
      a3 = fmaf(v0, bf2f(q0.w), a3);
    }
    if (overflow) {
      int seen = 0;
      const int have = rend - rbeg;
      for (int i = beg; i < end; ++i) {
        const int2 rec = bucketed[i];
        const int r8 = ((unsigned)rec.x) >> 24;
        if ((r8 >> 6) == q && (r8 & 63) == r) {
          ++seen;
          if (seen > have) {
            const float v0 = __int_as_float(rec.y);
            const ushort4 q0 =
                *(const ushort4*)(h + (size_t)(rec.x & 0x00FFFFFF) * FT + j);
            a0 = fmaf(v0, bf2f(q0.x), a0);
            a1 = fmaf(v0, bf2f(q0.y), a1);
            a2 = fmaf(v0, bf2f(q0.z), a2);
            a3 = fmaf(v0, bf2f(q0.w), a3);
          }
        }
      }
    }

    if (row < N_NODES) {
      float4 o;
      o.x = fmaxf(a0, 0.f);
      o.y = fmaxf(a1, 0.f);
      o.z = fmaxf(a2, 0.f);
      o.w = fmaxf(a3, 0.f);
      *(float4*)(out + (size_t)row * FT + j) = o;
    }
  }
}

// ---------------------------------------------------------------------------
// Fallback (small ws): standalone bf16-h gemm + atomic scatter + relu.
// ---------------------------------------------------------------------------
__global__ __launch_bounds__(256) void gemm_bias_kernel(
    const float* __restrict__ x,
    const float* __restrict__ W,
    const float* __restrict__ b,
    ushort* __restrict__ h) {
  __shared__ __align__(16) ushort whi[16384];
  const int tid = threadIdx.x;

  for (int idx = tid; idx < 16384; idx += 256) {
    const int k = idx >> 7;
    const int col = idx & 127;
    const ushort hi = f2bf(W[idx]);
    const int lane_ = (((k >> 3) & 3) << 4) | (col & 15);
    const int pos = ((((k >> 5) << 3) + (col >> 4)) * 64 + lane_) * 8 + (k & 7);
    whi[pos] = hi;
  }
  __syncthreads();

  const int w = tid >> 6;
  const int lane = tid & 63;
  const int r0 = blockIdx.x * 256 + w * 64;
  const int arow = lane & 15;
  const int kgrp = (lane >> 4) << 3;

  float bias_v[8];
#pragma unroll
  for (int ct = 0; ct < 8; ++ct) bias_v[ct] = b[ct * 16 + (lane & 15)];

  f32x4 acc[4][8];
#pragma unroll
  for (int rf = 0; rf < 4; ++rf)
#pragma unroll
    for (int ct = 0; ct < 8; ++ct) acc[rf][ct] = (f32x4){0.f, 0.f, 0.f, 0.f};

#pragma unroll
  for (int ks = 0; ks < 4; ++ks) {
    bf16x8 afr[4];
#pragma unroll
    for (int rf = 0; rf < 4; ++rf) {
      int r = r0 + rf * 16 + arow;
      r = (r < N_NODES) ? r : (N_NODES - 1);
      const float* xp = x + (size_t)r * FT + ks * 32 + kgrp;
      const float4 u0 = *(const float4*)xp;
      const float4 u1 = *(const float4*)(xp + 4);
      bf16x8 a;
      a[0] = (short)f2bf(u0.x);
      a[1] = (short)f2bf(u0.y);
      a[2] = (short)f2bf(u0.z);
      a[3] = (short)f2bf(u0.w);
      a[4] = (short)f2bf(u1.x);
      a[5] = (short)f2bf(u1.y);
      a[6] = (short)f2bf(u1.z);
      a[7] = (short)f2bf(u1.w);
      afr[rf] = a;
    }
#pragma unroll
    for (int ct = 0; ct < 8; ++ct) {
      const int fo = ((ks * 8 + ct) * 64 + lane) * 8;
      const bf16x8 bh = *(const bf16x8*)&whi[fo];
#pragma unroll
      for (int rf = 0; rf < 4; ++rf) {
        acc[rf][ct] = __builtin_amdgcn_mfma_f32_16x16x32_bf16(
            afr[rf], bh, acc[rf][ct], 0, 0, 0);
      }
    }
  }

  const int crow0 = (lane >> 4) << 2;
  const int ccol = lane & 15;
#pragma unroll
  for (int rf = 0; rf < 4; ++rf) {
#pragma unroll
    for (int ct = 0; ct < 8; ++ct) {
      const int col = ct * 16 + ccol;
#pragma unroll
      for (int i = 0; i < 4; ++i) {
        const int row = r0 + rf * 16 + crow0 + i;
        if (row < N_NODES)
          h[(size_t)row * FT + col] = f2bf(acc[rf][ct][i] + bias_v[ct]);
      }
    }
  }
}

__global__ __launch_bounds__(256) void edge_scatter_kernel(
    const int* __restrict__ erows,
    const int* __restrict__ ecols,
    const float* __restrict__ evals,
    const ushort* __restrict__ h,
    float* out) {
  const int tid = threadIdx.x;
  const int e = blockIdx.x * 8 + (tid >> 5);
  if (e >= N_EDGES) return;
  const int r = erows[e];
  const int c = ecols[e];
  const float v = evals[e];
  const int j = (tid & 31) * 4;
  const ushort4 q = *(const ushort4*)(h + (size_t)c * FT + j);
  float* op = out + (size_t)r * FT + j;
  atomicAdd(op + 0, v * bf2f(q.x));
  atomicAdd(op + 1, v * bf2f(q.y));
  atomicAdd(op + 2, v * bf2f(q.z));
  atomicAdd(op + 3, v * bf2f(q.w));
}

__global__ __launch_bounds__(256) void relu_kernel(float* out, int n4) {
  const int i = blockIdx.x * blockDim.x + threadIdx.x;
  if (i < n4) {
    float4 v = ((float4*)out)[i];
    v.x = fmaxf(v.x, 0.f);
    v.y = fmaxf(v.y, 0.f);
    v.z = fmaxf(v.z, 0.f);
    v.w = fmaxf(v.w, 0.f);
    ((float4*)out)[i] = v;
  }
}

extern "C" void kernel_launch(void* const* d_in, const int* in_sizes, int n_in,
                              void* d_out, int out_size, void* d_ws, size_t ws_size,
                              hipStream_t stream) {
  const float* x = (const float*)d_in[0];
  const int* erows = (const int*)d_in[1];
  const int* ecols = (const int*)d_in[2];
  const float* evals = (const float*)d_in[3];
  const float* W = (const float*)d_in[4];
  const float* b = (const float*)d_in[5];
  float* out = (float*)d_out;

  char* ws = (char*)d_ws;
  ushort* h = (ushort*)(ws + OFF_H);

  if (ws_size >= (size_t)WS_NEEDED) {
    int2* bucketed = (int2*)(ws + OFF_BUCKETED);
    int* blkhist = (int*)(ws + OFF_BLKHIST);
    int* btot = (int*)(ws + OFF_BTOT);
    int* bucket_base = (int*)(ws + OFF_BBASE);

    partA_kernel<<<NBLKP, 256, 0, stream>>>(erows, blkhist);
    partB1_kernel<<<NBUCK, 512, 0, stream>>>(blkhist, btot);
    partB2_kernel<<<1, 512, 0, stream>>>(btot, bucket_base);
    fused_gemm_partC_kernel<<<GEMM_BLOCKS + NBLKP, 256, 0, stream>>>(
        x, W, b, h, erows, ecols, evals, blkhist, bucket_base, bucketed);
    spmm_bucket_kernel<<<NBUCK * 4, 512, 0, stream>>>(bucketed, bucket_base,
                                                      h, out);
  } else {
    gemm_bias_kernel<<<GEMM_BLOCKS, 256, 0, stream>>>(x, W, b, h);
    hipMemsetAsync(d_out, 0, (size_t)out_size * sizeof(float), stream);
    edge_scatter_kernel<<<(N_EDGES + 7) / 8, 256, 0, stream>>>(erows, ecols,
                                                               evals, h, out);
    const int n4 = out_size / 4;
    relu_kernel<<<(n4 + 255) / 256, 256, 0, stream>>>(out, n4);
  }
}

// Round 18
// 115.580 us; speedup vs baseline: 1.3366x; 1.0190x over previous
//
#include <hip/hip_runtime.h>

#define N_NODES 100000
#define N_EDGES 1600000
#define FT 128

#define NBUCK 391   // partition buckets: 256 rows each (row >> 8)
#define EPB 4096    // edges per partition block
#define NBLKP ((N_EDGES + EPB - 1) / EPB)  // 391 partition blocks
#define CAP 1536    // staged edges per 64-row quarter (avg 1023, +16 sigma)
#define GEMM_BLOCKS ((N_NODES + 255) / 256)  // 391
#define SPMM_GRID (8 * 4 * ((NBUCK + 7) / 8))  // 1568 (4 dead blocks)

// ---- workspace layout (bytes) ----------------------------------------------
// h_bf        [0,           25,600,000)   N_NODES*FT*2 (bf16)
// bucketed    [25,600,000,  38,400,000)   N_EDGES int2 (packed row8|col, val)
// blkhist     [38,400,000,  39,011,524)   NBLKP*NBUCK ints (block-major)
// btot        [39,011,524,  39,013,088)   NBUCK ints
// bucket_base [39,013,088,  39,014,656)   NBUCK+1 ints
#define OFF_H 0
#define OFF_BUCKETED 25600000
#define OFF_BLKHIST 38400000
#define OFF_BTOT 39011524
#define OFF_BBASE 39013088
#define WS_NEEDED 39014656

typedef __attribute__((ext_vector_type(8))) short bf16x8;
typedef __attribute__((ext_vector_type(4))) float f32x4;

// bf16 helpers (RNE pack, shift-unpack).
static __device__ __forceinline__ ushort f2bf(float f) {
  const unsigned u = __float_as_uint(f);
  return (ushort)((u + 0x7FFF + ((u >> 16) & 1)) >> 16);
}
static __device__ __forceinline__ float bf2f(ushort s) {
  return __uint_as_float((unsigned)s << 16);
}

// ---------------------------------------------------------------------------
// Pass A: per-block LDS histogram over 256-row buckets.
// ---------------------------------------------------------------------------
__global__ __launch_bounds__(256) void partA_kernel(
    const int* __restrict__ erows, int* __restrict__ blkhist) {
  __shared__ int cnt[NBUCK];
  const int tid = threadIdx.x;
  for (int j = tid; j < NBUCK; j += 256) cnt[j] = 0;
  __syncthreads();

  const int base4 = blockIdx.x * (EPB / 4);
#pragma unroll
  for (int it = 0; it < EPB / 4 / 256; ++it) {
    const int idx4 = base4 + it * 256 + tid;
    if (idx4 < N_EDGES / 4) {
      const int4 r = ((const int4*)erows)[idx4];
      atomicAdd(&cnt[r.x >> 8], 1);
      atomicAdd(&cnt[r.y >> 8], 1);
      atomicAdd(&cnt[r.z >> 8], 1);
      atomicAdd(&cnt[r.w >> 8], 1);
    }
  }
  __syncthreads();
  int* dst = blkhist + (size_t)blockIdx.x * NBUCK;
  for (int j = tid; j < NBUCK; j += 256) dst[j] = cnt[j];
}

// ---------------------------------------------------------------------------
// Pass B1: per-bucket Hillis-Steele scan over partition blocks (grid=NBUCK).
// ---------------------------------------------------------------------------
__global__ __launch_bounds__(512) void partB1_kernel(
    int* __restrict__ blkhist, int* __restrict__ btot) {
  __shared__ int ps[512];
  const int b = blockIdx.x;
  const int t = threadIdx.x;
  int v = 0;
  if (t < NBLKP) v = blkhist[(size_t)t * NBUCK + b];
  ps[t] = v;
  __syncthreads();
#pragma unroll
  for (int d = 1; d < 512; d <<= 1) {
    const int u = (t >= d) ? ps[t - d] : 0;
    __syncthreads();
    ps[t] += u;
    __syncthreads();
  }
  if (t < NBLKP) blkhist[(size_t)t * NBUCK + b] = ps[t] - v;  // exclusive
  if (t == NBLKP - 1) btot[b] = ps[t];
}

// ---------------------------------------------------------------------------
// Pass B2: exclusive-scan btot -> bucket_base (+ sentinel).
// ---------------------------------------------------------------------------
__global__ __launch_bounds__(512) void partB2_kernel(
    const int* __restrict__ btot, int* __restrict__ bucket_base) {
  __shared__ int ps[512];
  const int t = threadIdx.x;
  int v = (t < NBUCK) ? btot[t] : 0;
  ps[t] = v;
  __syncthreads();
#pragma unroll
  for (int d = 1; d < 512; d <<= 1) {
    const int u = (t >= d) ? ps[t - d] : 0;
    __syncthreads();
    ps[t] += u;
    __syncthreads();
  }
  if (t < NBUCK) bucket_base[t] = ps[t] - v;
  if (t == NBUCK - 1) bucket_base[NBUCK] = N_EDGES;
}

// ---------------------------------------------------------------------------
// FUSED gemm + partC (unchanged from R17).
// ---------------------------------------------------------------------------
__global__ __launch_bounds__(256) void fused_gemm_partC_kernel(
    const float* __restrict__ x,
    const float* __restrict__ W,
    const float* __restrict__ b,
    ushort* __restrict__ h,
    const int* __restrict__ erows,
    const int* __restrict__ ecols,
    const float* __restrict__ evals,
    const int* __restrict__ blkhist,
    const int* __restrict__ bucket_base,
    int2* __restrict__ bucketed) {
  __shared__ __align__(16) ushort whi[16384];  // 32 KB (gemm half)
  __shared__ int cur[NBUCK];                   // 1.6 KB (partC half)
  const int tid = threadIdx.x;

  if (blockIdx.x < GEMM_BLOCKS) {
    for (int idx = tid; idx < 16384; idx += 256) {
      const int k = idx >> 7;
      const int col = idx & 127;
      const ushort hi = f2bf(W[idx]);
      const int lane_ = (((k >> 3) & 3) << 4) | (col & 15);
      const int pos =
          ((((k >> 5) << 3) + (col >> 4)) * 64 + lane_) * 8 + (k & 7);
      whi[pos] = hi;
    }
    __syncthreads();

    const int w = tid >> 6;
    const int lane = tid & 63;
    const int r0 = blockIdx.x * 256 + w * 64;
    const int arow = lane & 15;
    const int kgrp = (lane >> 4) << 3;

    float bias_v[8];
#pragma unroll
    for (int ct = 0; ct < 8; ++ct) bias_v[ct] = b[ct * 16 + (lane & 15)];

    f32x4 acc[4][8];
#pragma unroll
    for (int rf = 0; rf < 4; ++rf)
#pragma unroll
      for (int ct = 0; ct < 8; ++ct) acc[rf][ct] = (f32x4){0.f, 0.f, 0.f, 0.f};

#pragma unroll
    for (int ks = 0; ks < 4; ++ks) {
      bf16x8 afr[4];
#pragma unroll
      for (int rf = 0; rf < 4; ++rf) {
        int r = r0 + rf * 16 + arow;
        r = (r < N_NODES) ? r : (N_NODES - 1);
        const float* xp = x + (size_t)r * FT + ks * 32 + kgrp;
        const float4 u0 = *(const float4*)xp;
        const float4 u1 = *(const float4*)(xp + 4);
        bf16x8 a;
        a[0] = (short)f2bf(u0.x);
        a[1] = (short)f2bf(u0.y);
        a[2] = (short)f2bf(u0.z);
        a[3] = (short)f2bf(u0.w);
        a[4] = (short)f2bf(u1.x);
        a[5] = (short)f2bf(u1.y);
        a[6] = (short)f2bf(u1.z);
        a[7] = (short)f2bf(u1.w);
        afr[rf] = a;
      }
#pragma unroll
      for (int ct = 0; ct < 8; ++ct) {
        const int fo = ((ks * 8 + ct) * 64 + lane) * 8;
        const bf16x8 bh = *(const bf16x8*)&whi[fo];
#pragma unroll
        for (int rf = 0; rf < 4; ++rf) {
          acc[rf][ct] = __builtin_amdgcn_mfma_f32_16x16x32_bf16(
              afr[rf], bh, acc[rf][ct], 0, 0, 0);
        }
      }
    }

    const int crow0 = (lane >> 4) << 2;
    const int ccol = lane & 15;
#pragma unroll
    for (int rf = 0; rf < 4; ++rf) {
#pragma unroll
      for (int ct = 0; ct < 8; ++ct) {
        const int col = ct * 16 + ccol;
#pragma unroll
        for (int i = 0; i < 4; ++i) {
          const int row = r0 + rf * 16 + crow0 + i;
          if (row < N_NODES)
            h[(size_t)row * FT + col] = f2bf(acc[rf][ct][i] + bias_v[ct]);
        }
      }
    }
  } else {
    const int bid = blockIdx.x - GEMM_BLOCKS;
    const int* src = blkhist + (size_t)bid * NBUCK;
    for (int j = tid; j < NBUCK; j += 256) cur[j] = src[j] + bucket_base[j];
    __syncthreads();

    const int base4 = bid * (EPB / 4);
#pragma unroll
    for (int it = 0; it < EPB / 4 / 256; ++it) {
      const int idx4 = base4 + it * 256 + tid;
      if (idx4 < N_EDGES / 4) {
        const int4 r = ((const int4*)erows)[idx4];
        const int4 c = ((const int4*)ecols)[idx4];
        const float4 v = ((const float4*)evals)[idx4];
        int p;
        p = atomicAdd(&cur[r.x >> 8], 1);
        bucketed[p] = (int2){((r.x & 255) << 24) | c.x, __float_as_int(v.x)};
        p = atomicAdd(&cur[r.y >> 8], 1);
        bucketed[p] = (int2){((r.y & 255) << 24) | c.y, __float_as_int(v.y)};
        p = atomicAdd(&cur[r.z >> 8], 1);
        bucketed[p] = (int2){((r.z & 255) << 24) | c.z, __float_as_int(v.z)};
        p = atomicAdd(&cur[r.w >> 8], 1);
        bucketed[p] = (int2){((r.w & 255) << 24) | c.w, __float_as_int(v.w)};
      }
    }
  }
}

// ---------------------------------------------------------------------------
// Fused filter + sort + SpMM with XCD-aware swizzle: the 4 quarter-blocks of
// bucket b are mapped to the SAME XCD (blockIdx % 8 preserved across q) and
// adjacent in dispatch order, so the bucket-region re-read hits that XCD's
// L2 instead of refetching over the fabric 4x.
//   p = (b%8) + 8*(4*(b/8) + q);   inverse: x=p%8; m=p/8; q=m%4; b=8*(m/4)+x
// ---------------------------------------------------------------------------
__global__ __launch_bounds__(512) void spmm_bucket_kernel(
    const int2* __restrict__ bucketed,
    const int* __restrict__ bucket_base,
    const ushort* __restrict__ h,
    float* __restrict__ out) {
  __shared__ int2 tmp[CAP];   // 12 KB unsorted stage
  __shared__ int2 eds[CAP];   // 12 KB sorted
  __shared__ int cnt[64];
  __shared__ int pos[64];
  __shared__ int cur[64];
  __shared__ int ns;
  const int p_ = blockIdx.x;
  const int x_ = p_ & 7;
  const int m_ = p_ >> 3;
  const int q = m_ & 3;
  const int b = 8 * (m_ >> 2) + x_;
  if (b >= NBUCK) return;
  const int t = threadIdx.x;
  const int beg = bucket_base[b];
  const int end = bucket_base[b + 1];

  if (t < 64) cnt[t] = 0;
  if (t == 0) ns = 0;
  __syncthreads();

  for (int i = beg + t; i < end; i += 512) {
    const int2 rec = bucketed[i];
    const int r8 = ((unsigned)rec.x) >> 24;
    if ((r8 >> 6) == q) {
      const int p = atomicAdd(&ns, 1);
      if (p < CAP) {
        tmp[p] = rec;
        atomicAdd(&cnt[r8 & 63], 1);
      }
    }
  }
  __syncthreads();

  const int m = (ns < CAP) ? ns : CAP;
  const bool overflow = (ns > CAP);

  if (t < 64) pos[t] = cnt[t];
  __syncthreads();
#pragma unroll
  for (int d = 1; d < 64; d <<= 1) {
    int u = 0;
    if (t < 64 && t >= d) u = pos[t - d];
    __syncthreads();
    if (t < 64) pos[t] += u;
    __syncthreads();
  }
  if (t < 64) {
    const int excl = pos[t] - cnt[t];
    pos[t] = excl;
    cur[t] = excl;
  }
  __syncthreads();

  for (int i = t; i < m; i += 512) {
    const int2 rec = tmp[i];
    const int r6 = (((unsigned)rec.x) >> 24) & 63;
    const int p = atomicAdd(&cur[r6], 1);
    eds[p] = (int2){rec.x & 0x00FFFFFF, rec.y};
  }
  __syncthreads();

  const int g = t >> 5;
  const int lane = t & 31;
  const int j = lane * 4;

  for (int rr = 0; rr < 4; ++rr) {
    const int r = rr * 16 + g;
    const int row = b * 256 + q * 64 + r;
    const int rbeg = pos[r];
    const int rend = cur[r];

    float a0 = 0.f, a1 = 0.f, a2 = 0.f, a3 = 0.f;
    int e = rbeg;
    for (; e + 3 < rend; e += 4) {
      const int2 p0 = eds[e];
      const int2 p1 = eds[e + 1];
      const int2 p2 = eds[e + 2];
      const int2 p3 = eds[e + 3];
      const ushort4 q0 = *(const ushort4*)(h + (size_t)p0.x * FT + j);
      const ushort4 q1 = *(const ushort4*)(h + (size_t)p1.x * FT + j);
      const ushort4 q2 = *(const ushort4*)(h + (size_t)p2.x * FT + j);
      const ushort4 q3 = *(const ushort4*)(h + (size_t)p3.x * FT + j);
      const float v0 = __int_as_float(p0.y);
      const float v1 = __int_as_float(p1.y);
      const float v2 = __int_as_float(p2.y);
      const float v3 = __int_as_float(p3.y);
      a0 = fmaf(v0, bf2f(q0.x), a0);
      a1 = fmaf(v0, bf2f(q0.y), a1);
      a2 = fmaf(v0, bf2f(q0.z), a2);
      a3 = fmaf(v0, bf2f(q0.w), a3);
      a0 = fmaf(v1, bf2f(q1.x), a0);
      a1 = fmaf(v1, bf2f(q1.y), a1);
      a2 = fmaf(v1, bf2f(q1.z), a2);
      a3 = fmaf(v1, bf2f(q1.w), a3);
      a0 = fmaf(v2, bf2f(q2.x), a0);
      a1 = fmaf(v2, bf2f(q2.y), a1);
      a2 = fmaf(v2, bf2f(q2.z), a2);
      a3 = fmaf(v2, bf2f(q2.w), a3);
      a0 = fmaf(v3, bf2f(q3.x), a0);
      a1 = fmaf(v3, bf2f(q3.y), a1);
      a2 = fmaf(v3, bf2f(q3.z), a2);
      a3 = fmaf(v3, bf2f(q3.w), a3);
    }
    for (; e < rend; ++e) {
      const int2 p0 = eds[e];
      const float v0 = __int_as_float(p0.y);
      const ushort4 q0 = *(const ushort4*)(h + (size_t)p0.x * FT + j);
      a0 = fmaf(v0, bf2f(q0.x), a0);
      a1 = fmaf(v0, bf2f(q0.y), a1);
      a2 = fmaf(v0, bf2f(q0.z), a2);
      a3 = fmaf(v0, bf2f(q0.w), a3);
    }
    if (overflow) {
      int seen = 0;
      const int have = rend - rbeg;
      for (int i = beg; i < end; ++i) {
        const int2 rec = bucketed[i];
        const int r8 = ((unsigned)rec.x) >> 24;
        if ((r8 >> 6) == q && (r8 & 63) == r) {
          ++seen;
          if (seen > have) {
            const float v0 = __int_as_float(rec.y);
            const ushort4 q0 =
                *(const ushort4*)(h + (size_t)(rec.x & 0x00FFFFFF) * FT + j);
            a0 = fmaf(v0, bf2f(q0.x), a0);
            a1 = fmaf(v0, bf2f(q0.y), a1);
            a2 = fmaf(v0, bf2f(q0.z), a2);
            a3 = fmaf(v0, bf2f(q0.w), a3);
          }
        }
      }
    }

    if (row < N_NODES) {
      float4 o;
      o.x = fmaxf(a0, 0.f);
      o.y = fmaxf(a1, 0.f);
      o.z = fmaxf(a2, 0.f);
      o.w = fmaxf(a3, 0.f);
      *(float4*)(out + (size_t)row * FT + j) = o;
    }
  }
}

// ---------------------------------------------------------------------------
// Fallback (small ws): standalone bf16-h gemm + atomic scatter + relu.
// ---------------------------------------------------------------------------
__global__ __launch_bounds__(256) void gemm_bias_kernel(
    const float* __restrict__ x,
    const float* __restrict__ W,
    const float* __restrict__ b,
    ushort* __restrict__ h) {
  __shared__ __align__(16) ushort whi[16384];
  const int tid = threadIdx.x;

  for (int idx = tid; idx < 16384; idx += 256) {
    const int k = idx >> 7;
    const int col = idx & 127;
    const ushort hi = f2bf(W[idx]);
    const int lane_ = (((k >> 3) & 3) << 4) | (col & 15);
    const int pos = ((((k >> 5) << 3) + (col >> 4)) * 64 + lane_) * 8 + (k & 7);
    whi[pos] = hi;
  }
  __syncthreads();

  const int w = tid >> 6;
  const int lane = tid & 63;
  const int r0 = blockIdx.x * 256 + w * 64;
  const int arow = lane & 15;
  const int kgrp = (lane >> 4) << 3;

  float bias_v[8];
#pragma unroll
  for (int ct = 0; ct < 8; ++ct) bias_v[ct] = b[ct * 16 + (lane & 15)];

  f32x4 acc[4][8];
#pragma unroll
  for (int rf = 0; rf < 4; ++rf)
#pragma unroll
    for (int ct = 0; ct < 8; ++ct) acc[rf][ct] = (f32x4){0.f, 0.f, 0.f, 0.f};

#pragma unroll
  for (int ks = 0; ks < 4; ++ks) {
    bf16x8 afr[4];
#pragma unroll
    for (int rf = 0; rf < 4; ++rf) {
      int r = r0 + rf * 16 + arow;
      r = (r < N_NODES) ? r : (N_NODES - 1);
      const float* xp = x + (size_t)r * FT + ks * 32 + kgrp;
      const float4 u0 = *(const float4*)xp;
      const float4 u1 = *(const float4*)(xp + 4);
      bf16x8 a;
      a[0] = (short)f2bf(u0.x);
      a[1] = (short)f2bf(u0.y);
      a[2] = (short)f2bf(u0.z);
      a[3] = (short)f2bf(u0.w);
      a[4] = (short)f2bf(u1.x);
      a[5] = (short)f2bf(u1.y);
      a[6] = (short)f2bf(u1.z);
      a[7] = (short)f2bf(u1.w);
      afr[rf] = a;
    }
#pragma unroll
    for (int ct = 0; ct < 8; ++ct) {
      const int fo = ((ks * 8 + ct) * 64 + lane) * 8;
      const bf16x8 bh = *(const bf16x8*)&whi[fo];
#pragma unroll
      for (int rf = 0; rf < 4; ++rf) {
        acc[rf][ct] = __builtin_amdgcn_mfma_f32_16x16x32_bf16(
            afr[rf], bh, acc[rf][ct], 0, 0, 0);
      }
    }
  }

  const int crow0 = (lane >> 4) << 2;
  const int ccol = lane & 15;
#pragma unroll
  for (int rf = 0; rf < 4; ++rf) {
#pragma unroll
    for (int ct = 0; ct < 8; ++ct) {
      const int col = ct * 16 + ccol;
#pragma unroll
      for (int i = 0; i < 4; ++i) {
        const int row = r0 + rf * 16 + crow0 + i;
        if (row < N_NODES)
          h[(size_t)row * FT + col] = f2bf(acc[rf][ct][i] + bias_v[ct]);
      }
    }
  }
}

__global__ __launch_bounds__(256) void edge_scatter_kernel(
    const int* __restrict__ erows,
    const int* __restrict__ ecols,
    const float* __restrict__ evals,
    const ushort* __restrict__ h,
    float* out) {
  const int tid = threadIdx.x;
  const int e = blockIdx.x * 8 + (tid >> 5);
  if (e >= N_EDGES) return;
  const int r = erows[e];
  const int c = ecols[e];
  const float v = evals[e];
  const int j = (tid & 31) * 4;
  const ushort4 q = *(const ushort4*)(h + (size_t)c * FT + j);
  float* op = out + (size_t)r * FT + j;
  atomicAdd(op + 0, v * bf2f(q.x));
  atomicAdd(op + 1, v * bf2f(q.y));
  atomicAdd(op + 2, v * bf2f(q.z));
  atomicAdd(op + 3, v * bf2f(q.w));
}

__global__ __launch_bounds__(256) void relu_kernel(float* out, int n4) {
  const int i = blockIdx.x * blockDim.x + threadIdx.x;
  if (i < n4) {
    float4 v = ((float4*)out)[i];
    v.x = fmaxf(v.x, 0.f);
    v.y = fmaxf(v.y, 0.f);
    v.z = fmaxf(v.z, 0.f);
    v.w = fmaxf(v.w, 0.f);
    ((float4*)out)[i] = v;
  }
}

extern "C" void kernel_launch(void* const* d_in, const int* in_sizes, int n_in,
                              void* d_out, int out_size, void* d_ws, size_t ws_size,
                              hipStream_t stream) {
  const float* x = (const float*)d_in[0];
  const int* erows = (const int*)d_in[1];
  const int* ecols = (const int*)d_in[2];
  const float* evals = (const float*)d_in[3];
  const float* W = (const float*)d_in[4];
  const float* b = (const float*)d_in[5];
  float* out = (float*)d_out;

  char* ws = (char*)d_ws;
  ushort* h = (ushort*)(ws + OFF_H);

  if (ws_size >= (size_t)WS_NEEDED) {
    int2* bucketed = (int2*)(ws + OFF_BUCKETED);
    int* blkhist = (int*)(ws + OFF_BLKHIST);
    int* btot = (int*)(ws + OFF_BTOT);
    int* bucket_base = (int*)(ws + OFF_BBASE);

    partA_kernel<<<NBLKP, 256, 0, stream>>>(erows, blkhist);
    partB1_kernel<<<NBUCK, 512, 0, stream>>>(blkhist, btot);
    partB2_kernel<<<1, 512, 0, stream>>>(btot, bucket_base);
    fused_gemm_partC_kernel<<<GEMM_BLOCKS + NBLKP, 256, 0, stream>>>(
        x, W, b, h, erows, ecols, evals, blkhist, bucket_base, bucketed);
    spmm_bucket_kernel<<<SPMM_GRID, 512, 0, stream>>>(bucketed, bucket_base,
                                                      h, out);
  } else {
    gemm_bias_kernel<<<GEMM_BLOCKS, 256, 0, stream>>>(x, W, b, h);
    hipMemsetAsync(d_out, 0, (size_t)out_size * sizeof(float), stream);
    edge_scatter_kernel<<<(N_EDGES + 7) / 8, 256, 0, stream>>>(erows, ecols,
                                                               evals, h, out);
    const int n4 = out_size / 4;
    relu_kernel<<<(n4 + 255) / 256, 256, 0, stream>>>(out, n4);
  }
}

// Round 19
// 106.691 us; speedup vs baseline: 1.4479x; 1.0833x over previous
//
#include <hip/hip_runtime.h>

#define N_NODES 100000
#define N_EDGES 1600000
#define FT 128

#define NBUCK 391   // partition buckets: 256 rows each (row >> 8)
#define EPB 4096    // edges per partition block
#define NBLKP ((N_EDGES + EPB - 1) / EPB)  // 391 partition blocks
#define CAP 1536    // LDS-staged edges per 64-row quarter (avg 1023, +16 sigma)
#define CAPB 4800   // region capacity per bucket (avg 4092, +11 sigma)
#define OVFCAP 65536
#define GEMM_BLOCKS ((N_NODES + 255) / 256)  // 391
#define SPMM_GRID (8 * 4 * ((NBUCK + 7) / 8))  // 1568 (4 dead blocks)

// ---- workspace layout (bytes) ----------------------------------------------
// h_bf       [0,           25,600,000)   N_NODES*FT*2 (bf16)
// bucketed   [25,600,000,  40,614,400)   NBUCK regions x CAPB int2
// gcur       [40,614,400,  40,615,964)   NBUCK ints (bucket fill counts)
// novf       [40,615,964,  40,615,968)   1 int (overflow count)
// ovf_rec    [40,615,968,  41,140,256)   OVFCAP int2
// ovf_buck   [41,140,256,  41,402,400)   OVFCAP ints
#define OFF_H 0
#define OFF_BUCKETED 25600000
#define OFF_GCUR 40614400
#define OFF_NOVF 40615964
#define OFF_OVFREC 40615968
#define OFF_OVFBUCK 41140256
#define WS_NEEDED 41402400

typedef __attribute__((ext_vector_type(8))) short bf16x8;
typedef __attribute__((ext_vector_type(4))) float f32x4;

// bf16 helpers (RNE pack, shift-unpack).
static __device__ __forceinline__ ushort f2bf(float f) {
  const unsigned u = __float_as_uint(f);
  return (ushort)((u + 0x7FFF + ((u >> 16) & 1)) >> 16);
}
static __device__ __forceinline__ float bf2f(ushort s) {
  return __uint_as_float((unsigned)s << 16);
}

// ---------------------------------------------------------------------------
// FUSED gemm + partC2: grid = GEMM_BLOCKS + NBLKP.
// gemm half: MFMA projection h = x@W + b (bf16 out), unchanged from R18.
// partC2 half: LDS histogram (pass 1) -> bulk atomic reservation (one
// with-return atomicAdd per non-empty bucket: base in that bucket's fixed
// CAPB region) -> scatter (pass 2). Replaces partA+partB1+partB2+partC:
// no global scan, no blkhist. Overflow beyond CAPB spills to a global list
// (statistically never; spmm checks a single counter).
// ---------------------------------------------------------------------------
__global__ __launch_bounds__(256) void fused_gemm_partC_kernel(
    const float* __restrict__ x,
    const float* __restrict__ W,
    const float* __restrict__ b,
    ushort* __restrict__ h,
    const int* __restrict__ erows,
    const int* __restrict__ ecols,
    const float* __restrict__ evals,
    int* gcur,
    int* novf,
    int2* __restrict__ ovf_rec,
    int* __restrict__ ovf_buck,
    int2* __restrict__ bucketed) {
  __shared__ __align__(16) ushort whi[16384];  // 32 KB (gemm half)
  __shared__ int cnt[NBUCK];                   // hist -> absolute cursor
  const int tid = threadIdx.x;

  if (blockIdx.x < GEMM_BLOCKS) {
    // ------------------------- gemm half ---------------------------------
    for (int idx = tid; idx < 16384; idx += 256) {
      const int k = idx >> 7;
      const int col = idx & 127;
      const ushort hi = f2bf(W[idx]);
      const int lane_ = (((k >> 3) & 3) << 4) | (col & 15);
      const int pos =
          ((((k >> 5) << 3) + (col >> 4)) * 64 + lane_) * 8 + (k & 7);
      whi[pos] = hi;
    }
    __syncthreads();

    const int w = tid >> 6;
    const int lane = tid & 63;
    const int r0 = blockIdx.x * 256 + w * 64;
    const int arow = lane & 15;
    const int kgrp = (lane >> 4) << 3;

    float bias_v[8];
#pragma unroll
    for (int ct = 0; ct < 8; ++ct) bias_v[ct] = b[ct * 16 + (lane & 15)];

    f32x4 acc[4][8];
#pragma unroll
    for (int rf = 0; rf < 4; ++rf)
#pragma unroll
      for (int ct = 0; ct < 8; ++ct) acc[rf][ct] = (f32x4){0.f, 0.f, 0.f, 0.f};

#pragma unroll
    for (int ks = 0; ks < 4; ++ks) {
      bf16x8 afr[4];
#pragma unroll
      for (int rf = 0; rf < 4; ++rf) {
        int r = r0 + rf * 16 + arow;
        r = (r < N_NODES) ? r : (N_NODES - 1);
        const float* xp = x + (size_t)r * FT + ks * 32 + kgrp;
        const float4 u0 = *(const float4*)xp;
        const float4 u1 = *(const float4*)(xp + 4);
        bf16x8 a;
        a[0] = (short)f2bf(u0.x);
        a[1] = (short)f2bf(u0.y);
        a[2] = (short)f2bf(u0.z);
        a[3] = (short)f2bf(u0.w);
        a[4] = (short)f2bf(u1.x);
        a[5] = (short)f2bf(u1.y);
        a[6] = (short)f2bf(u1.z);
        a[7] = (short)f2bf(u1.w);
        afr[rf] = a;
      }
#pragma unroll
      for (int ct = 0; ct < 8; ++ct) {
        const int fo = ((ks * 8 + ct) * 64 + lane) * 8;
        const bf16x8 bh = *(const bf16x8*)&whi[fo];
#pragma unroll
        for (int rf = 0; rf < 4; ++rf) {
          acc[rf][ct] = __builtin_amdgcn_mfma_f32_16x16x32_bf16(
              afr[rf], bh, acc[rf][ct], 0, 0, 0);
        }
      }
    }

    const int crow0 = (lane >> 4) << 2;
    const int ccol = lane & 15;
#pragma unroll
    for (int rf = 0; rf < 4; ++rf) {
#pragma unroll
      for (int ct = 0; ct < 8; ++ct) {
        const int col = ct * 16 + ccol;
#pragma unroll
        for (int i = 0; i < 4; ++i) {
          const int row = r0 + rf * 16 + crow0 + i;
          if (row < N_NODES)
            h[(size_t)row * FT + col] = f2bf(acc[rf][ct][i] + bias_v[ct]);
        }
      }
    }
  } else {
    // ------------------------- partC2 half -------------------------------
    const int bid = blockIdx.x - GEMM_BLOCKS;
    for (int j = tid; j < NBUCK; j += 256) cnt[j] = 0;
    __syncthreads();

    const int base4 = bid * (EPB / 4);
    // pass 1: histogram
#pragma unroll
    for (int it = 0; it < EPB / 4 / 256; ++it) {
      const int idx4 = base4 + it * 256 + tid;
      if (idx4 < N_EDGES / 4) {
        const int4 r = ((const int4*)erows)[idx4];
        atomicAdd(&cnt[r.x >> 8], 1);
        atomicAdd(&cnt[r.y >> 8], 1);
        atomicAdd(&cnt[r.z >> 8], 1);
        atomicAdd(&cnt[r.w >> 8], 1);
      }
    }
    __syncthreads();

    // bulk reservation: one with-return atomic per non-empty bucket
    for (int j = tid; j < NBUCK; j += 256) {
      const int hj = cnt[j];
      int base = 0;
      if (hj > 0) base = atomicAdd(&gcur[j], hj);
      // absolute cursor; cap enforced per-record at write time
      cnt[j] = j * CAPB + ((base < CAPB) ? base : CAPB);
    }
    __syncthreads();

    // pass 2: scatter
#pragma unroll
    for (int it = 0; it < EPB / 4 / 256; ++it) {
      const int idx4 = base4 + it * 256 + tid;
      if (idx4 < N_EDGES / 4) {
        const int4 r = ((const int4*)erows)[idx4];
        const int4 c = ((const int4*)ecols)[idx4];
        const float4 v = ((const float4*)evals)[idx4];
        int bb, p, lim;
        int2 rec;
#define SCAT(RR, CC, VV)                                           \
        bb = (RR) >> 8;                                            \
        rec.x = (((RR) & 255) << 24) | (CC);                       \
        rec.y = __float_as_int(VV);                                \
        p = atomicAdd(&cnt[bb], 1);                                \
        lim = bb * CAPB + CAPB;                                    \
        if (p < lim) {                                             \
          bucketed[p] = rec;                                       \
        } else {                                                   \
          const int op = atomicAdd(novf, 1);                       \
          if (op < OVFCAP) { ovf_rec[op] = rec; ovf_buck[op] = bb; } \
        }
        SCAT(r.x, c.x, v.x)
        SCAT(r.y, c.y, v.y)
        SCAT(r.z, c.z, v.z)
        SCAT(r.w, c.w, v.w)
#undef SCAT
      }
    }
  }
}

// ---------------------------------------------------------------------------
// Fused filter + sort + SpMM with XCD-aware swizzle (unchanged structure;
// bucket region is now [b*CAPB, b*CAPB + min(gcur[b],CAPB)) and the global
// overflow list is scanned only if novf > 0).
// ---------------------------------------------------------------------------
__global__ __launch_bounds__(512) void spmm_bucket_kernel(
    const int2* __restrict__ bucketed,
    const int* __restrict__ gcur,
    const int* __restrict__ novf,
    const int2* __restrict__ ovf_rec,
    const int* __restrict__ ovf_buck,
    const ushort* __restrict__ h,
    float* __restrict__ out) {
  __shared__ int2 tmp[CAP];   // 12 KB unsorted stage
  __shared__ int2 eds[CAP];   // 12 KB sorted
  __shared__ int cnt[64];
  __shared__ int pos[64];
  __shared__ int cur[64];
  __shared__ int ns;
  const int p_ = blockIdx.x;
  const int x_ = p_ & 7;
  const int m_ = p_ >> 3;
  const int q = m_ & 3;
  const int b = 8 * (m_ >> 2) + x_;
  if (b >= NBUCK) return;
  const int t = threadIdx.x;
  const int beg = b * CAPB;
  const int fill = gcur[b];
  const int end = beg + ((fill < CAPB) ? fill : CAPB);
  const int nov = *novf;

  if (t < 64) cnt[t] = 0;
  if (t == 0) ns = 0;
  __syncthreads();

  for (int i = beg + t; i < end; i += 512) {
    const int2 rec = bucketed[i];
    const int r8 = ((unsigned)rec.x) >> 24;
    if ((r8 >> 6) == q) {
      const int p = atomicAdd(&ns, 1);
      if (p < CAP) {
        tmp[p] = rec;
        atomicAdd(&cnt[r8 & 63], 1);
      }
    }
  }
  __syncthreads();

  const int m = (ns < CAP) ? ns : CAP;
  const bool overflow = (ns > CAP);

  if (t < 64) pos[t] = cnt[t];
  __syncthreads();
#pragma unroll
  for (int d = 1; d < 64; d <<= 1) {
    int u = 0;
    if (t < 64 && t >= d) u = pos[t - d];
    __syncthreads();
    if (t < 64) pos[t] += u;
    __syncthreads();
  }
  if (t < 64) {
    const int excl = pos[t] - cnt[t];
    pos[t] = excl;
    cur[t] = excl;
  }
  __syncthreads();

  for (int i = t; i < m; i += 512) {
    const int2 rec = tmp[i];
    const int r6 = (((unsigned)rec.x) >> 24) & 63;
    const int p = atomicAdd(&cur[r6], 1);
    eds[p] = (int2){rec.x & 0x00FFFFFF, rec.y};
  }
  __syncthreads();

  const int g = t >> 5;
  const int lane = t & 31;
  const int j = lane * 4;

  for (int rr = 0; rr < 4; ++rr) {
    const int r = rr * 16 + g;
    const int row = b * 256 + q * 64 + r;
    const int rbeg = pos[r];
    const int rend = cur[r];

    float a0 = 0.f, a1 = 0.f, a2 = 0.f, a3 = 0.f;
    int e = rbeg;
    for (; e + 3 < rend; e += 4) {
      const int2 p0 = eds[e];
      const int2 p1 = eds[e + 1];
      const int2 p2 = eds[e + 2];
      const int2 p3 = eds[e + 3];
      const ushort4 q0 = *(const ushort4*)(h + (size_t)p0.x * FT + j);
      const ushort4 q1 = *(const ushort4*)(h + (size_t)p1.x * FT + j);
      const ushort4 q2 = *(const ushort4*)(h + (size_t)p2.x * FT + j);
      const ushort4 q3 = *(const ushort4*)(h + (size_t)p3.x * FT + j);
      const float v0 = __int_as_float(p0.y);
      const float v1 = __int_as_float(p1.y);
      const float v2 = __int_as_float(p2.y);
      const float v3 = __int_as_float(p3.y);
      a0 = fmaf(v0, bf2f(q0.x), a0);
      a1 = fmaf(v0, bf2f(q0.y), a1);
      a2 = fmaf(v0, bf2f(q0.z), a2);
      a3 = fmaf(v0, bf2f(q0.w), a3);
      a0 = fmaf(v1, bf2f(q1.x), a0);
      a1 = fmaf(v1, bf2f(q1.y), a1);
      a2 = fmaf(v1, bf2f(q1.z), a2);
      a3 = fmaf(v1, bf2f(q1.w), a3);
      a0 = fmaf(v2, bf2f(q2.x), a0);
      a1 = fmaf(v2, bf2f(q2.y), a1);
      a2 = fmaf(v2, bf2f(q2.z), a2);
      a3 = fmaf(v2, bf2f(q2.w), a3);
      a0 = fmaf(v3, bf2f(q3.x), a0);
      a1 = fmaf(v3, bf2f(q3.y), a1);
      a2 = fmaf(v3, bf2f(q3.z), a2);
      a3 = fmaf(v3, bf2f(q3.w), a3);
    }
    for (; e < rend; ++e) {
      const int2 p0 = eds[e];
      const float v0 = __int_as_float(p0.y);
      const ushort4 q0 = *(const ushort4*)(h + (size_t)p0.x * FT + j);
      a0 = fmaf(v0, bf2f(q0.x), a0);
      a1 = fmaf(v0, bf2f(q0.y), a1);
      a2 = fmaf(v0, bf2f(q0.z), a2);
      a3 = fmaf(v0, bf2f(q0.w), a3);
    }
    if (overflow) {  // LDS stage overflow: rescan this bucket's region
      int seen = 0;
      const int have = rend - rbeg;
      for (int i = beg; i < end; ++i) {
        const int2 rec = bucketed[i];
        const int r8 = ((unsigned)rec.x) >> 24;
        if ((r8 >> 6) == q && (r8 & 63) == r) {
          ++seen;
          if (seen > have) {
            const float v0 = __int_as_float(rec.y);
            const ushort4 q0 =
                *(const ushort4*)(h + (size_t)(rec.x & 0x00FFFFFF) * FT + j);
            a0 = fmaf(v0, bf2f(q0.x), a0);
            a1 = fmaf(v0, bf2f(q0.y), a1);
            a2 = fmaf(v0, bf2f(q0.z), a2);
            a3 = fmaf(v0, bf2f(q0.w), a3);
          }
        }
      }
    }
    if (nov > 0) {  // global region overflow: scan spill list (never taken)
      const int lim = (nov < OVFCAP) ? nov : OVFCAP;
      for (int i = 0; i < lim; ++i) {
        if (ovf_buck[i] == b) {
          const int2 rec = ovf_rec[i];
          const int r8 = ((unsigned)rec.x) >> 24;
          if ((r8 >> 6) == q && (r8 & 63) == r) {
            const float v0 = __int_as_float(rec.y);
            const ushort4 q0 =
                *(const ushort4*)(h + (size_t)(rec.x & 0x00FFFFFF) * FT + j);
            a0 = fmaf(v0, bf2f(q0.x), a0);
            a1 = fmaf(v0, bf2f(q0.y), a1);
            a2 = fmaf(v0, bf2f(q0.z), a2);
            a3 = fmaf(v0, bf2f(q0.w), a3);
          }
        }
      }
    }

    if (row < N_NODES) {
      float4 o;
      o.x = fmaxf(a0, 0.f);
      o.y = fmaxf(a1, 0.f);
      o.z = fmaxf(a2, 0.f);
      o.w = fmaxf(a3, 0.f);
      *(float4*)(out + (size_t)row * FT + j) = o;
    }
  }
}

// ---------------------------------------------------------------------------
// Fallback (small ws): standalone bf16-h gemm + atomic scatter + relu.
// ---------------------------------------------------------------------------
__global__ __launch_bounds__(256) void gemm_bias_kernel(
    const float* __restrict__ x,
    const float* __restrict__ W,
    const float* __restrict__ b,
    ushort* __restrict__ h) {
  __shared__ __align__(16) ushort whi[16384];
  const int tid = threadIdx.x;

  for (int idx = tid; idx < 16384; idx += 256) {
    const int k = idx >> 7;
    const int col = idx & 127;
    const ushort hi = f2bf(W[idx]);
    const int lane_ = (((k >> 3) & 3) << 4) | (col & 15);
    const int pos = ((((k >> 5) << 3) + (col >> 4)) * 64 + lane_) * 8 + (k & 7);
    whi[pos] = hi;
  }
  __syncthreads();

  const int w = tid >> 6;
  const int lane = tid & 63;
  const int r0 = blockIdx.x * 256 + w * 64;
  const int arow = lane & 15;
  const int kgrp = (lane >> 4) << 3;

  float bias_v[8];
#pragma unroll
  for (int ct = 0; ct < 8; ++ct) bias_v[ct] = b[ct * 16 + (lane & 15)];

  f32x4 acc[4][8];
#pragma unroll
  for (int rf = 0; rf < 4; ++rf)
#pragma unroll
    for (int ct = 0; ct < 8; ++ct) acc[rf][ct] = (f32x4){0.f, 0.f, 0.f, 0.f};

#pragma unroll
  for (int ks = 0; ks < 4; ++ks) {
    bf16x8 afr[4];
#pragma unroll
    for (int rf = 0; rf < 4; ++rf) {
      int r = r0 + rf * 16 + arow;
      r = (r < N_NODES) ? r : (N_NODES - 1);
      const float* xp = x + (size_t)r * FT + ks * 32 + kgrp;
      const float4 u0 = *(const float4*)xp;
      const float4 u1 = *(const float4*)(xp + 4);
      bf16x8 a;
      a[0] = (short)f2bf(u0.x);
      a[1] = (short)f2bf(u0.y);
      a[2] = (short)f2bf(u0.z);
      a[3] = (short)f2bf(u0.w);
      a[4] = (short)f2bf(u1.x);
      a[5] = (short)f2bf(u1.y);
      a[6] = (short)f2bf(u1.z);
      a[7] = (short)f2bf(u1.w);
      afr[rf] = a;
    }
#pragma unroll
    for (int ct = 0; ct < 8; ++ct) {
      const int fo = ((ks * 8 + ct) * 64 + lane) * 8;
      const bf16x8 bh = *(const bf16x8*)&whi[fo];
#pragma unroll
      for (int rf = 0; rf < 4; ++rf) {
        acc[rf][ct] = __builtin_amdgcn_mfma_f32_16x16x32_bf16(
            afr[rf], bh, acc[rf][ct], 0, 0, 0);
      }
    }
  }

  const int crow0 = (lane >> 4) << 2;
  const int ccol = lane & 15;
#pragma unroll
  for (int rf = 0; rf < 4; ++rf) {
#pragma unroll
    for (int ct = 0; ct < 8; ++ct) {
      const int col = ct * 16 + ccol;
#pragma unroll
      for (int i = 0; i < 4; ++i) {
        const int row = r0 + rf * 16 + crow0 + i;
        if (row < N_NODES)
          h[(size_t)row * FT + col] = f2bf(acc[rf][ct][i] + bias_v[ct]);
      }
    }
  }
}

__global__ __launch_bounds__(256) void edge_scatter_kernel(
    const int* __restrict__ erows,
    const int* __restrict__ ecols,
    const float* __restrict__ evals,
    const ushort* __restrict__ h,
    float* out) {
  const int tid = threadIdx.x;
  const int e = blockIdx.x * 8 + (tid >> 5);
  if (e >= N_EDGES) return;
  const int r = erows[e];
  const int c = ecols[e];
  const float v = evals[e];
  const int j = (tid & 31) * 4;
  const ushort4 q = *(const ushort4*)(h + (size_t)c * FT + j);
  float* op = out + (size_t)r * FT + j;
  atomicAdd(op + 0, v * bf2f(q.x));
  atomicAdd(op + 1, v * bf2f(q.y));
  atomicAdd(op + 2, v * bf2f(q.z));
  atomicAdd(op + 3, v * bf2f(q.w));
}

__global__ __launch_bounds__(256) void relu_kernel(float* out, int n4) {
  const int i = blockIdx.x * blockDim.x + threadIdx.x;
  if (i < n4) {
    float4 v = ((float4*)out)[i];
    v.x = fmaxf(v.x, 0.f);
    v.y = fmaxf(v.y, 0.f);
    v.z = fmaxf(v.z, 0.f);
    v.w = fmaxf(v.w, 0.f);
    ((float4*)out)[i] = v;
  }
}

extern "C" void kernel_launch(void* const* d_in, const int* in_sizes, int n_in,
                              void* d_out, int out_size, void* d_ws, size_t ws_size,
                              hipStream_t stream) {
  const float* x = (const float*)d_in[0];
  const int* erows = (const int*)d_in[1];
  const int* ecols = (const int*)d_in[2];
  const float* evals = (const float*)d_in[3];
  const float* W = (const float*)d_in[4];
  const float* b = (const float*)d_in[5];
  float* out = (float*)d_out;

  char* ws = (char*)d_ws;
  ushort* h = (ushort*)(ws + OFF_H);

  if (ws_size >= (size_t)WS_NEEDED) {
    int2* bucketed = (int2*)(ws + OFF_BUCKETED);
    int* gcur = (int*)(ws + OFF_GCUR);
    int* novf = (int*)(ws + OFF_NOVF);
    int2* ovf_rec = (int2*)(ws + OFF_OVFREC);
    int* ovf_buck = (int*)(ws + OFF_OVFBUCK);

    // zero gcur (NBUCK ints) + novf (1 int) — contiguous
    hipMemsetAsync(gcur, 0, (NBUCK + 1) * sizeof(int), stream);
    fused_gemm_partC_kernel<<<GEMM_BLOCKS + NBLKP, 256, 0, stream>>>(
        x, W, b, h, erows, ecols, evals, gcur, novf, ovf_rec, ovf_buck,
        bucketed);
    spmm_bucket_kernel<<<SPMM_GRID, 512, 0, stream>>>(
        bucketed, gcur, novf, ovf_rec, ovf_buck, h, out);
  } else {
    gemm_bias_kernel<<<GEMM_BLOCKS, 256, 0, stream>>>(x, W, b, h);
    hipMemsetAsync(d_out, 0, (size_t)out_size * sizeof(float), stream);
    edge_scatter_kernel<<<(N_EDGES + 7) / 8, 256, 0, stream>>>(erows, ecols,
                                                               evals, h, out);
    const int n4 = out_size / 4;
    relu_kernel<<<(n4 + 255) / 256, 256, 0, stream>>>(out, n4);
  }
}